// Round 1
// baseline (1154.328 us; speedup 1.0000x reference)
//
#include <hip/hip_runtime.h>

#define N_NODES 50000
#define N_EDGES 800000
#define NODE_FEAT 176
#define HIDDEN 64
#define LN_EPS 1e-5f

__device__ __forceinline__ float wave_sum64(float v) {
#pragma unroll
    for (int o = 32; o > 0; o >>= 1) v += __shfl_xor(v, o);
    return v;
}

// ---------------- Kernel 1: h = x @ in_w + in_b ----------------
// wave-per-node: lane j computes h[node][j]; in_w staged in LDS (44KB).
__global__ __launch_bounds__(256) void k_inproj(const float* __restrict__ x,
                                                const float* __restrict__ w,
                                                const float* __restrict__ b,
                                                float* __restrict__ h) {
    __shared__ float lw[NODE_FEAT * HIDDEN];  // 176*64*4 = 45056 B
    const int tid = threadIdx.x;
    for (int i = tid; i < NODE_FEAT * HIDDEN; i += 256) lw[i] = w[i];
    __syncthreads();
    const int wv = tid >> 6, lane = tid & 63;
    for (int node = blockIdx.x * 4 + wv; node < N_NODES; node += gridDim.x * 4) {
        float acc = b[lane];
        const float* xrow = x + (size_t)node * NODE_FEAT;
#pragma unroll 4
        for (int k = 0; k < NODE_FEAT; k += 4) {
            float4 xv = *reinterpret_cast<const float4*>(xrow + k);  // broadcast
            acc = fmaf(xv.x, lw[(k + 0) * HIDDEN + lane], acc);
            acc = fmaf(xv.y, lw[(k + 1) * HIDDEN + lane], acc);
            acc = fmaf(xv.z, lw[(k + 2) * HIDDEN + lane], acc);
            acc = fmaf(xv.w, lw[(k + 3) * HIDDEN + lane], acc);
        }
        h[(size_t)node * HIDDEN + lane] = acc;
    }
}

// ---------------- Kernel 2: edge message + scatter ----------------
// wave-per-edge: lane j = feature j. e_j = edge_attr@edge_w + b, msg = relu(h[src]+e),
// atomicAdd into aggr[dst].
__global__ __launch_bounds__(256) void k_edge(const float* __restrict__ h,
                                              const float* __restrict__ ea,
                                              const int* __restrict__ ei,
                                              const float* __restrict__ ew,
                                              const float* __restrict__ eb,
                                              float* __restrict__ aggr) {
    const int gt = blockIdx.x * 256 + threadIdx.x;
    const int e = gt >> 6;
    if (e >= N_EDGES) return;
    const int lane = threadIdx.x & 63;
    const int src = ei[e];
    const int dst = ei[N_EDGES + e];
    const float4 a = *reinterpret_cast<const float4*>(ea + (size_t)e * 4);  // broadcast
    float v = eb[lane];
    v = fmaf(a.x, ew[0 * HIDDEN + lane], v);
    v = fmaf(a.y, ew[1 * HIDDEN + lane], v);
    v = fmaf(a.z, ew[2 * HIDDEN + lane], v);
    v = fmaf(a.w, ew[3 * HIDDEN + lane], v);
    v += h[(size_t)src * HIDDEN + lane];
    v = fmaxf(v, 0.0f);
    atomicAdd(&aggr[(size_t)dst * HIDDEN + lane], v);
}

// ---------------- Kernel 3: fused node update ----------------
// z = h + aggr; z1 = relu(z@w1+b1) [128]; z2 = z1@w2+b2 [64];
// h = relu(layernorm(z2)). wave-per-node, w1 in LDS (32KB), w2 via L1/L2.
__global__ __launch_bounds__(256) void k_update(float* __restrict__ h,
                                                const float* __restrict__ aggr,
                                                const float* __restrict__ w1,
                                                const float* __restrict__ b1,
                                                const float* __restrict__ w2,
                                                const float* __restrict__ b2,
                                                const float* __restrict__ lng,
                                                const float* __restrict__ lnb) {
    __shared__ float lw1[HIDDEN * 128];  // 32768 B
    __shared__ float zb[4][HIDDEN];
    __shared__ float z1b[4][128];
    const int tid = threadIdx.x;
    for (int i = tid; i < HIDDEN * 128; i += 256) lw1[i] = w1[i];
    __syncthreads();
    const int wv = tid >> 6, lane = tid & 63;
    const float gam = lng[lane], bet = lnb[lane];
    const float bb1a = b1[lane], bb1b = b1[lane + 64], bb2 = b2[lane];
    for (int base = blockIdx.x * 4; base < N_NODES; base += gridDim.x * 4) {
        const int node = base + wv;
        const bool valid = node < N_NODES;
        float z = 0.0f;
        if (valid) z = h[(size_t)node * HIDDEN + lane] + aggr[(size_t)node * HIDDEN + lane];
        zb[wv][lane] = z;
        __syncthreads();
        float acc0 = bb1a, acc1 = bb1b;
#pragma unroll 8
        for (int k = 0; k < HIDDEN; ++k) {
            float zk = zb[wv][k];  // broadcast
            acc0 = fmaf(zk, lw1[k * 128 + lane], acc0);
            acc1 = fmaf(zk, lw1[k * 128 + 64 + lane], acc1);
        }
        z1b[wv][lane] = fmaxf(acc0, 0.0f);
        z1b[wv][lane + 64] = fmaxf(acc1, 0.0f);
        __syncthreads();
        float acc = bb2;
#pragma unroll 8
        for (int k = 0; k < 128; ++k) {
            acc = fmaf(z1b[wv][k], w2[k * HIDDEN + lane], acc);
        }
        // layernorm over the 64 lanes
        float mu = wave_sum64(acc) * (1.0f / 64.0f);
        float d = acc - mu;
        float var = wave_sum64(d * d) * (1.0f / 64.0f);
        float r = rsqrtf(var + LN_EPS);
        float hn = fmaxf(fmaf(gam * d, r, bet), 0.0f);
        if (valid) h[(size_t)node * HIDDEN + lane] = hn;
        __syncthreads();
    }
}

// ---------------- Kernel 4: global add pool ----------------
__global__ __launch_bounds__(256) void k_pool(const float* __restrict__ h,
                                              float* __restrict__ g) {
    __shared__ float red[256];
    const int tid = threadIdx.x;
    const int lane = tid & 63;
    float part = 0.0f;
    for (int i = blockIdx.x * 4 + (tid >> 6); i < N_NODES; i += gridDim.x * 4)
        part += h[(size_t)i * HIDDEN + lane];
    red[tid] = part;
    __syncthreads();
    if (tid < 64) {
        float s = red[tid] + red[tid + 64] + red[tid + 128] + red[tid + 192];
        atomicAdd(&g[tid], s);
    }
}

// ---------------- Kernel 5: regressor ----------------
// out = relu(g @ reg_w1 + b1) @ reg_w2 + b2.  One wave.
__global__ __launch_bounds__(64) void k_reg(const float* __restrict__ g,
                                            const float* __restrict__ w1,
                                            const float* __restrict__ b1,
                                            const float* __restrict__ w2,
                                            const float* __restrict__ b2,
                                            float* __restrict__ out) {
    const int j = threadIdx.x;
    const int jm = j & 31;
    float acc = b1[jm];
#pragma unroll 8
    for (int k = 0; k < 64; ++k) {
        float gk = g[k];  // broadcast
        acc = fmaf(gk, w1[k * 32 + jm], acc);
    }
    float contrib = (j < 32) ? fmaxf(acc, 0.0f) * w2[jm] : 0.0f;
    float s = wave_sum64(contrib);
    if (j == 0) out[0] = s + b2[0];
}

extern "C" void kernel_launch(void* const* d_in, const int* in_sizes, int n_in,
                              void* d_out, int out_size, void* d_ws, size_t ws_size,
                              hipStream_t stream) {
    const float* x     = (const float*)d_in[0];
    const int*   ei    = (const int*)d_in[1];
    const float* ea    = (const float*)d_in[2];
    const float* in_w  = (const float*)d_in[3];
    const float* in_b  = (const float*)d_in[4];
    const float* edge_w = (const float*)d_in[5];   // (4,4,64)
    const float* edge_b = (const float*)d_in[6];   // (4,64)
    const float* mlp_w1 = (const float*)d_in[7];   // (4,64,128)
    const float* mlp_b1 = (const float*)d_in[8];   // (4,128)
    const float* mlp_w2 = (const float*)d_in[9];   // (4,128,64)
    const float* mlp_b2 = (const float*)d_in[10];  // (4,64)
    const float* ln_g   = (const float*)d_in[11];  // (4,64)
    const float* ln_b   = (const float*)d_in[12];  // (4,64)
    const float* reg_w1 = (const float*)d_in[13];  // (64,32)
    const float* reg_b1 = (const float*)d_in[14];  // (32,)
    const float* reg_w2 = (const float*)d_in[15];  // (32,1)
    const float* reg_b2 = (const float*)d_in[16];  // (1,)

    float* h    = (float*)d_ws;
    float* aggr = h + (size_t)N_NODES * HIDDEN;
    float* g    = aggr + (size_t)N_NODES * HIDDEN;
    float* outf = (float*)d_out;

    k_inproj<<<1024, 256, 0, stream>>>(x, in_w, in_b, h);

    const size_t aggr_bytes = (size_t)N_NODES * HIDDEN * sizeof(float);
    const int edge_blocks = (N_EDGES * 64) / 256;  // 200000
    for (int l = 0; l < 4; ++l) {
        hipMemsetAsync(aggr, 0, aggr_bytes, stream);
        k_edge<<<edge_blocks, 256, 0, stream>>>(h, ea, ei,
                                                edge_w + l * 4 * HIDDEN,
                                                edge_b + l * HIDDEN, aggr);
        k_update<<<1024, 256, 0, stream>>>(h, aggr,
                                           mlp_w1 + l * HIDDEN * 128,
                                           mlp_b1 + l * 128,
                                           mlp_w2 + l * 128 * HIDDEN,
                                           mlp_b2 + l * HIDDEN,
                                           ln_g + l * HIDDEN,
                                           ln_b + l * HIDDEN);
    }

    hipMemsetAsync(g, 0, HIDDEN * sizeof(float), stream);
    k_pool<<<256, 256, 0, stream>>>(h, g);
    k_reg<<<1, 64, 0, stream>>>(g, reg_w1, reg_b1, reg_w2, reg_b2, outf);
}

// Round 2
// 988.813 us; speedup vs baseline: 1.1674x; 1.1674x over previous
//
#include <hip/hip_runtime.h>

#define N_NODES 50000
#define N_EDGES 800000
#define NODE_FEAT 176
#define HIDDEN 64
#define LN_EPS 1e-5f

__device__ __forceinline__ float wave_sum64(float v) {
#pragma unroll
    for (int o = 32; o > 0; o >>= 1) v += __shfl_xor(v, o);
    return v;
}

// ---------------- Kernel 1: h = x @ in_w + in_b ----------------
__global__ __launch_bounds__(256) void k_inproj(const float* __restrict__ x,
                                                const float* __restrict__ w,
                                                const float* __restrict__ b,
                                                float* __restrict__ h) {
    __shared__ float lw[NODE_FEAT * HIDDEN];  // 45056 B
    const int tid = threadIdx.x;
    for (int i = tid; i < NODE_FEAT * HIDDEN; i += 256) lw[i] = w[i];
    __syncthreads();
    const int wv = tid >> 6, lane = tid & 63;
    for (int node = blockIdx.x * 4 + wv; node < N_NODES; node += gridDim.x * 4) {
        float acc = b[lane];
        const float* xrow = x + (size_t)node * NODE_FEAT;
#pragma unroll 4
        for (int k = 0; k < NODE_FEAT; k += 4) {
            float4 xv = *reinterpret_cast<const float4*>(xrow + k);
            acc = fmaf(xv.x, lw[(k + 0) * HIDDEN + lane], acc);
            acc = fmaf(xv.y, lw[(k + 1) * HIDDEN + lane], acc);
            acc = fmaf(xv.z, lw[(k + 2) * HIDDEN + lane], acc);
            acc = fmaf(xv.w, lw[(k + 3) * HIDDEN + lane], acc);
        }
        h[(size_t)node * HIDDEN + lane] = acc;
    }
}

// ---------------- CSR build ----------------
__global__ __launch_bounds__(256) void k_hist(const int* __restrict__ ei,
                                              int* __restrict__ cnt) {
    int e = blockIdx.x * 256 + threadIdx.x;
    if (e < N_EDGES) atomicAdd(&cnt[ei[N_EDGES + e]], 1);
}

__global__ __launch_bounds__(1024) void k_scan(const int* __restrict__ cnt,
                                               int* __restrict__ row_ptr,
                                               int* __restrict__ cursor) {
    __shared__ int part[1024];
    const int t = threadIdx.x;
    const int beg = t * 49;
    const int end = min(beg + 49, N_NODES);
    int s = 0;
    for (int i = beg; i < end; ++i) s += cnt[i];
    part[t] = s;
    __syncthreads();
    for (int off = 1; off < 1024; off <<= 1) {
        int v = (t >= off) ? part[t - off] : 0;
        __syncthreads();
        part[t] += v;
        __syncthreads();
    }
    int run = (t == 0) ? 0 : part[t - 1];
    for (int i = beg; i < end; ++i) {
        row_ptr[i] = run;
        cursor[i] = run;
        run += cnt[i];
    }
    if (t == 1023) row_ptr[N_NODES] = part[1023];
}

// scatter edges into dst-sorted order; pre-permute src ids and edge_attr
__global__ __launch_bounds__(256) void k_scatter(const int* __restrict__ ei,
                                                 const float4* __restrict__ ea,
                                                 int* __restrict__ cursor,
                                                 int* __restrict__ srcs,
                                                 float4* __restrict__ ea_s) {
    int e = blockIdx.x * 256 + threadIdx.x;
    if (e >= N_EDGES) return;
    int d = ei[N_EDGES + e];
    int pos = atomicAdd(&cursor[d], 1);
    srcs[pos] = ei[e];
    ea_s[pos] = ea[e];
}

// ---------------- Fused layer ----------------
// per node: aggr over CSR in-edges (gather h_in[src], edge proj, relu, reg-acc),
// z = h_in[node] + aggr, MLP 64->128->64, layernorm, relu -> h_out.
__global__ __launch_bounds__(256) void k_layer(const float* __restrict__ h_in,
                                               float* __restrict__ h_out,
                                               const int* __restrict__ row_ptr,
                                               const int* __restrict__ srcs,
                                               const float4* __restrict__ ea_s,
                                               const float* __restrict__ ew,
                                               const float* __restrict__ eb,
                                               const float* __restrict__ w1,
                                               const float* __restrict__ b1,
                                               const float* __restrict__ w2,
                                               const float* __restrict__ b2,
                                               const float* __restrict__ lng,
                                               const float* __restrict__ lnb) {
    __shared__ float lw1[HIDDEN * 128];  // 32 KB
    __shared__ float zb[4][HIDDEN];
    __shared__ float z1b[4][128];
    const int tid = threadIdx.x;
    for (int i = tid; i < HIDDEN * 128; i += 256) lw1[i] = w1[i];
    __syncthreads();
    const int wv = tid >> 6, lane = tid & 63;
    const float ew0 = ew[0 * HIDDEN + lane], ew1 = ew[1 * HIDDEN + lane];
    const float ew2 = ew[2 * HIDDEN + lane], ew3 = ew[3 * HIDDEN + lane];
    const float ebl = eb[lane];
    const float gam = lng[lane], bet = lnb[lane];
    const float bb1a = b1[lane], bb1b = b1[lane + 64], bb2 = b2[lane];

    for (int base = blockIdx.x * 4; base < N_NODES; base += gridDim.x * 4) {
        const int node = base + wv;
        const bool valid = node < N_NODES;
        int beg = 0, end = 0;
        float acc = 0.0f;
        if (valid) {
            beg = row_ptr[node];
            end = row_ptr[node + 1];
            acc = h_in[(size_t)node * HIDDEN + lane];
        }
        int i = beg;
        for (; i + 1 < end; i += 2) {
            int s0 = srcs[i], s1 = srcs[i + 1];
            float4 a0 = ea_s[i], a1 = ea_s[i + 1];
            float g0 = h_in[(size_t)s0 * HIDDEN + lane];
            float g1 = h_in[(size_t)s1 * HIDDEN + lane];
            float v0 = ebl;
            v0 = fmaf(a0.x, ew0, v0); v0 = fmaf(a0.y, ew1, v0);
            v0 = fmaf(a0.z, ew2, v0); v0 = fmaf(a0.w, ew3, v0);
            float v1 = ebl;
            v1 = fmaf(a1.x, ew0, v1); v1 = fmaf(a1.y, ew1, v1);
            v1 = fmaf(a1.z, ew2, v1); v1 = fmaf(a1.w, ew3, v1);
            acc += fmaxf(v0 + g0, 0.0f);
            acc += fmaxf(v1 + g1, 0.0f);
        }
        if (i < end) {
            int s0 = srcs[i];
            float4 a0 = ea_s[i];
            float g0 = h_in[(size_t)s0 * HIDDEN + lane];
            float v0 = ebl;
            v0 = fmaf(a0.x, ew0, v0); v0 = fmaf(a0.y, ew1, v0);
            v0 = fmaf(a0.z, ew2, v0); v0 = fmaf(a0.w, ew3, v0);
            acc += fmaxf(v0 + g0, 0.0f);
        }
        zb[wv][lane] = acc;
        __syncthreads();
        float acc0 = bb1a, acc1 = bb1b;
#pragma unroll 8
        for (int k = 0; k < HIDDEN; ++k) {
            float zk = zb[wv][k];
            acc0 = fmaf(zk, lw1[k * 128 + lane], acc0);
            acc1 = fmaf(zk, lw1[k * 128 + 64 + lane], acc1);
        }
        z1b[wv][lane] = fmaxf(acc0, 0.0f);
        z1b[wv][lane + 64] = fmaxf(acc1, 0.0f);
        __syncthreads();
        float a2 = bb2;
#pragma unroll 8
        for (int k = 0; k < 128; ++k) {
            a2 = fmaf(z1b[wv][k], w2[k * HIDDEN + lane], a2);
        }
        float mu = wave_sum64(a2) * (1.0f / 64.0f);
        float d = a2 - mu;
        float var = wave_sum64(d * d) * (1.0f / 64.0f);
        float r = rsqrtf(var + LN_EPS);
        float hn = fmaxf(fmaf(gam * d, r, bet), 0.0f);
        if (valid) h_out[(size_t)node * HIDDEN + lane] = hn;
        __syncthreads();
    }
}

// ---------------- pool + regressor ----------------
__global__ __launch_bounds__(256) void k_pool(const float* __restrict__ h,
                                              float* __restrict__ g) {
    __shared__ float red[256];
    const int tid = threadIdx.x;
    const int lane = tid & 63;
    float part = 0.0f;
    for (int i = blockIdx.x * 4 + (tid >> 6); i < N_NODES; i += gridDim.x * 4)
        part += h[(size_t)i * HIDDEN + lane];
    red[tid] = part;
    __syncthreads();
    if (tid < 64) {
        float s = red[tid] + red[tid + 64] + red[tid + 128] + red[tid + 192];
        atomicAdd(&g[tid], s);
    }
}

__global__ __launch_bounds__(64) void k_reg(const float* __restrict__ g,
                                            const float* __restrict__ w1,
                                            const float* __restrict__ b1,
                                            const float* __restrict__ w2,
                                            const float* __restrict__ b2,
                                            float* __restrict__ out) {
    const int j = threadIdx.x;
    const int jm = j & 31;
    float acc = b1[jm];
#pragma unroll 8
    for (int k = 0; k < 64; ++k) {
        float gk = g[k];
        acc = fmaf(gk, w1[k * 32 + jm], acc);
    }
    float contrib = (j < 32) ? fmaxf(acc, 0.0f) * w2[jm] : 0.0f;
    float s = wave_sum64(contrib);
    if (j == 0) out[0] = s + b2[0];
}

extern "C" void kernel_launch(void* const* d_in, const int* in_sizes, int n_in,
                              void* d_out, int out_size, void* d_ws, size_t ws_size,
                              hipStream_t stream) {
    const float* x      = (const float*)d_in[0];
    const int*   ei     = (const int*)d_in[1];
    const float* ea     = (const float*)d_in[2];
    const float* in_w   = (const float*)d_in[3];
    const float* in_b   = (const float*)d_in[4];
    const float* edge_w = (const float*)d_in[5];
    const float* edge_b = (const float*)d_in[6];
    const float* mlp_w1 = (const float*)d_in[7];
    const float* mlp_b1 = (const float*)d_in[8];
    const float* mlp_w2 = (const float*)d_in[9];
    const float* mlp_b2 = (const float*)d_in[10];
    const float* ln_g   = (const float*)d_in[11];
    const float* ln_b   = (const float*)d_in[12];
    const float* reg_w1 = (const float*)d_in[13];
    const float* reg_b1 = (const float*)d_in[14];
    const float* reg_w2 = (const float*)d_in[15];
    const float* reg_b2 = (const float*)d_in[16];

    // workspace layout
    char* ws = (char*)d_ws;
    float*  h0      = (float*)ws;                 ws += (size_t)N_NODES * HIDDEN * 4;
    float*  h1      = (float*)ws;                 ws += (size_t)N_NODES * HIDDEN * 4;
    float4* ea_s    = (float4*)ws;                ws += (size_t)N_EDGES * 16;
    int*    srcs    = (int*)ws;                   ws += (size_t)N_EDGES * 4;
    int*    row_ptr = (int*)ws;                   ws += (size_t)(N_NODES + 1) * 4;
    int*    cursor  = (int*)ws;                   ws += (size_t)N_NODES * 4;
    float*  g       = (float*)ws;                 ws += HIDDEN * 4;
    float*  outf    = (float*)d_out;

    const int eb_blocks = (N_EDGES + 255) / 256;

    // CSR build (once; reused by all layers)
    hipMemsetAsync(cursor, 0, N_NODES * sizeof(int), stream);
    k_hist<<<eb_blocks, 256, 0, stream>>>(ei, cursor);
    k_scan<<<1, 1024, 0, stream>>>(cursor, row_ptr, cursor);
    k_scatter<<<eb_blocks, 256, 0, stream>>>(ei, (const float4*)ea, cursor, srcs, ea_s);

    k_inproj<<<1024, 256, 0, stream>>>(x, in_w, in_b, h0);

    float* hin = h0;
    float* hout = h1;
    for (int l = 0; l < 4; ++l) {
        k_layer<<<1024, 256, 0, stream>>>(hin, hout, row_ptr, srcs, ea_s,
                                          edge_w + l * 4 * HIDDEN,
                                          edge_b + l * HIDDEN,
                                          mlp_w1 + l * HIDDEN * 128,
                                          mlp_b1 + l * 128,
                                          mlp_w2 + l * 128 * HIDDEN,
                                          mlp_b2 + l * HIDDEN,
                                          ln_g + l * HIDDEN,
                                          ln_b + l * HIDDEN);
        float* t = hin; hin = hout; hout = t;
    }

    hipMemsetAsync(g, 0, HIDDEN * sizeof(float), stream);
    k_pool<<<256, 256, 0, stream>>>(hin, g);
    k_reg<<<1, 64, 0, stream>>>(g, reg_w1, reg_b1, reg_w2, reg_b2, outf);
}

// Round 3
// 821.097 us; speedup vs baseline: 1.4058x; 1.2043x over previous
//
#include <hip/hip_runtime.h>

#define N_NODES 50000
#define N_EDGES 800000
#define NODE_FEAT 176
#define HIDDEN 64
#define LN_EPS 1e-5f

__device__ __forceinline__ float wave_sum64(float v) {
#pragma unroll
    for (int o = 32; o > 0; o >>= 1) v += __shfl_xor(v, o);
    return v;
}

// ---------------- Kernel 1: h = x @ in_w + in_b ----------------
__global__ __launch_bounds__(256) void k_inproj(const float* __restrict__ x,
                                                const float* __restrict__ w,
                                                const float* __restrict__ b,
                                                float* __restrict__ h) {
    __shared__ float lw[NODE_FEAT * HIDDEN];  // 45056 B
    const int tid = threadIdx.x;
    for (int i = tid; i < NODE_FEAT * HIDDEN; i += 256) lw[i] = w[i];
    __syncthreads();
    const int wv = tid >> 6, lane = tid & 63;
    for (int node = blockIdx.x * 4 + wv; node < N_NODES; node += gridDim.x * 4) {
        float acc = b[lane];
        const float* xrow = x + (size_t)node * NODE_FEAT;
#pragma unroll 4
        for (int k = 0; k < NODE_FEAT; k += 4) {
            float4 xv = *reinterpret_cast<const float4*>(xrow + k);
            acc = fmaf(xv.x, lw[(k + 0) * HIDDEN + lane], acc);
            acc = fmaf(xv.y, lw[(k + 1) * HIDDEN + lane], acc);
            acc = fmaf(xv.z, lw[(k + 2) * HIDDEN + lane], acc);
            acc = fmaf(xv.w, lw[(k + 3) * HIDDEN + lane], acc);
        }
        h[(size_t)node * HIDDEN + lane] = acc;
    }
}

// ---------------- CSR build ----------------
__global__ __launch_bounds__(256) void k_hist(const int* __restrict__ ei,
                                              int* __restrict__ cnt) {
    int e = blockIdx.x * 256 + threadIdx.x;
    if (e < N_EDGES) atomicAdd(&cnt[ei[N_EDGES + e]], 1);
}

__global__ __launch_bounds__(1024) void k_scan(const int* __restrict__ cnt,
                                               int* __restrict__ row_ptr,
                                               int* __restrict__ cursor) {
    __shared__ int part[1024];
    const int t = threadIdx.x;
    const int beg = t * 49;
    const int end = min(beg + 49, N_NODES);
    int s = 0;
    for (int i = beg; i < end; ++i) s += cnt[i];
    part[t] = s;
    __syncthreads();
    for (int off = 1; off < 1024; off <<= 1) {
        int v = (t >= off) ? part[t - off] : 0;
        __syncthreads();
        part[t] += v;
        __syncthreads();
    }
    int run = (t == 0) ? 0 : part[t - 1];
    for (int i = beg; i < end; ++i) {
        row_ptr[i] = run;
        cursor[i] = run;
        run += cnt[i];
    }
    if (t == 1023) row_ptr[N_NODES] = part[1023];
}

__global__ __launch_bounds__(256) void k_scatter(const int* __restrict__ ei,
                                                 const float4* __restrict__ ea,
                                                 int* __restrict__ cursor,
                                                 int* __restrict__ srcs,
                                                 float4* __restrict__ ea_s) {
    int e = blockIdx.x * 256 + threadIdx.x;
    if (e >= N_EDGES) return;
    int d = ei[N_EDGES + e];
    int pos = atomicAdd(&cursor[d], 1);
    srcs[pos] = ei[e];
    ea_s[pos] = ea[e];
}

// ---------------- Kernel A: gather + aggregate ----------------
// one wave per node; lane j = feature j. z = h_in[node] + sum relu(h_in[src]+e)
__global__ __launch_bounds__(256) void k_aggr(const float* __restrict__ h_in,
                                              float* __restrict__ z,
                                              const int* __restrict__ row_ptr,
                                              const int* __restrict__ srcs,
                                              const float4* __restrict__ ea_s,
                                              const float* __restrict__ ew,
                                              const float* __restrict__ eb) {
    const int wv = threadIdx.x >> 6, lane = threadIdx.x & 63;
    const int node = blockIdx.x * 4 + wv;  // grid sized exactly: 12500*4 = 50000
    const float ew0 = ew[0 * HIDDEN + lane], ew1 = ew[1 * HIDDEN + lane];
    const float ew2 = ew[2 * HIDDEN + lane], ew3 = ew[3 * HIDDEN + lane];
    const float ebl = eb[lane];
    const int beg = row_ptr[node];
    const int end = row_ptr[node + 1];
    float acc = h_in[(size_t)node * HIDDEN + lane];
    int i = beg;
    for (; i + 3 < end; i += 4) {
        const int s0 = srcs[i], s1 = srcs[i + 1], s2 = srcs[i + 2], s3 = srcs[i + 3];
        const float4 a0 = ea_s[i], a1 = ea_s[i + 1], a2 = ea_s[i + 2], a3 = ea_s[i + 3];
        const float g0 = h_in[(size_t)s0 * HIDDEN + lane];
        const float g1 = h_in[(size_t)s1 * HIDDEN + lane];
        const float g2 = h_in[(size_t)s2 * HIDDEN + lane];
        const float g3 = h_in[(size_t)s3 * HIDDEN + lane];
        float v0 = fmaf(a0.x, ew0, fmaf(a0.y, ew1, fmaf(a0.z, ew2, fmaf(a0.w, ew3, ebl))));
        float v1 = fmaf(a1.x, ew0, fmaf(a1.y, ew1, fmaf(a1.z, ew2, fmaf(a1.w, ew3, ebl))));
        float v2 = fmaf(a2.x, ew0, fmaf(a2.y, ew1, fmaf(a2.z, ew2, fmaf(a2.w, ew3, ebl))));
        float v3 = fmaf(a3.x, ew0, fmaf(a3.y, ew1, fmaf(a3.z, ew2, fmaf(a3.w, ew3, ebl))));
        acc += fmaxf(v0 + g0, 0.0f);
        acc += fmaxf(v1 + g1, 0.0f);
        acc += fmaxf(v2 + g2, 0.0f);
        acc += fmaxf(v3 + g3, 0.0f);
    }
    for (; i < end; ++i) {
        const int s0 = srcs[i];
        const float4 a0 = ea_s[i];
        const float g0 = h_in[(size_t)s0 * HIDDEN + lane];
        float v0 = fmaf(a0.x, ew0, fmaf(a0.y, ew1, fmaf(a0.z, ew2, fmaf(a0.w, ew3, ebl))));
        acc += fmaxf(v0 + g0, 0.0f);
    }
    z[(size_t)node * HIDDEN + lane] = acc;
}

// ---------------- Kernel B: MLP + LN + relu ----------------
__global__ __launch_bounds__(256) void k_mlp(const float* __restrict__ z,
                                             float* __restrict__ h_out,
                                             const float* __restrict__ w1,
                                             const float* __restrict__ b1,
                                             const float* __restrict__ w2,
                                             const float* __restrict__ b2,
                                             const float* __restrict__ lng,
                                             const float* __restrict__ lnb) {
    __shared__ float lw1[HIDDEN * 128];  // 32 KB
    __shared__ float zb[4][HIDDEN];
    __shared__ float z1b[4][128];
    const int tid = threadIdx.x;
    for (int i = tid; i < HIDDEN * 128; i += 256) lw1[i] = w1[i];
    __syncthreads();
    const int wv = tid >> 6, lane = tid & 63;
    const float gam = lng[lane], bet = lnb[lane];
    const float bb1a = b1[lane], bb1b = b1[lane + 64], bb2 = b2[lane];
    for (int base = blockIdx.x * 4; base < N_NODES; base += gridDim.x * 4) {
        const int node = base + wv;
        const bool valid = node < N_NODES;
        float zv = 0.0f;
        if (valid) zv = z[(size_t)node * HIDDEN + lane];
        zb[wv][lane] = zv;
        __syncthreads();
        float acc0 = bb1a, acc1 = bb1b;
#pragma unroll 8
        for (int k = 0; k < HIDDEN; ++k) {
            float zk = zb[wv][k];
            acc0 = fmaf(zk, lw1[k * 128 + lane], acc0);
            acc1 = fmaf(zk, lw1[k * 128 + 64 + lane], acc1);
        }
        z1b[wv][lane] = fmaxf(acc0, 0.0f);
        z1b[wv][lane + 64] = fmaxf(acc1, 0.0f);
        __syncthreads();
        float a2 = bb2;
#pragma unroll 8
        for (int k = 0; k < 128; ++k) {
            a2 = fmaf(z1b[wv][k], w2[k * HIDDEN + lane], a2);
        }
        float mu = wave_sum64(a2) * (1.0f / 64.0f);
        float d = a2 - mu;
        float var = wave_sum64(d * d) * (1.0f / 64.0f);
        float r = rsqrtf(var + LN_EPS);
        float hn = fmaxf(fmaf(gam * d, r, bet), 0.0f);
        if (valid) h_out[(size_t)node * HIDDEN + lane] = hn;
        __syncthreads();
    }
}

// ---------------- pool + regressor ----------------
__global__ __launch_bounds__(256) void k_pool(const float* __restrict__ h,
                                              float* __restrict__ g) {
    __shared__ float red[256];
    const int tid = threadIdx.x;
    const int lane = tid & 63;
    float part = 0.0f;
    for (int i = blockIdx.x * 4 + (tid >> 6); i < N_NODES; i += gridDim.x * 4)
        part += h[(size_t)i * HIDDEN + lane];
    red[tid] = part;
    __syncthreads();
    if (tid < 64) {
        float s = red[tid] + red[tid + 64] + red[tid + 128] + red[tid + 192];
        atomicAdd(&g[tid], s);
    }
}

__global__ __launch_bounds__(64) void k_reg(const float* __restrict__ g,
                                            const float* __restrict__ w1,
                                            const float* __restrict__ b1,
                                            const float* __restrict__ w2,
                                            const float* __restrict__ b2,
                                            float* __restrict__ out) {
    const int j = threadIdx.x;
    const int jm = j & 31;
    float acc = b1[jm];
#pragma unroll 8
    for (int k = 0; k < 64; ++k) {
        float gk = g[k];
        acc = fmaf(gk, w1[k * 32 + jm], acc);
    }
    float contrib = (j < 32) ? fmaxf(acc, 0.0f) * w2[jm] : 0.0f;
    float s = wave_sum64(contrib);
    if (j == 0) out[0] = s + b2[0];
}

extern "C" void kernel_launch(void* const* d_in, const int* in_sizes, int n_in,
                              void* d_out, int out_size, void* d_ws, size_t ws_size,
                              hipStream_t stream) {
    const float* x      = (const float*)d_in[0];
    const int*   ei     = (const int*)d_in[1];
    const float* ea     = (const float*)d_in[2];
    const float* in_w   = (const float*)d_in[3];
    const float* in_b   = (const float*)d_in[4];
    const float* edge_w = (const float*)d_in[5];
    const float* edge_b = (const float*)d_in[6];
    const float* mlp_w1 = (const float*)d_in[7];
    const float* mlp_b1 = (const float*)d_in[8];
    const float* mlp_w2 = (const float*)d_in[9];
    const float* mlp_b2 = (const float*)d_in[10];
    const float* ln_g   = (const float*)d_in[11];
    const float* ln_b   = (const float*)d_in[12];
    const float* reg_w1 = (const float*)d_in[13];
    const float* reg_b1 = (const float*)d_in[14];
    const float* reg_w2 = (const float*)d_in[15];
    const float* reg_b2 = (const float*)d_in[16];

    // workspace layout
    char* ws = (char*)d_ws;
    float*  h0      = (float*)ws;                 ws += (size_t)N_NODES * HIDDEN * 4;
    float*  h1      = (float*)ws;                 ws += (size_t)N_NODES * HIDDEN * 4;
    float*  zbuf    = (float*)ws;                 ws += (size_t)N_NODES * HIDDEN * 4;
    float4* ea_s    = (float4*)ws;                ws += (size_t)N_EDGES * 16;
    int*    srcs    = (int*)ws;                   ws += (size_t)N_EDGES * 4;
    int*    row_ptr = (int*)ws;                   ws += (size_t)(N_NODES + 1) * 4;
    int*    cursor  = (int*)ws;                   ws += (size_t)N_NODES * 4;
    float*  g       = (float*)ws;                 ws += HIDDEN * 4;
    float*  outf    = (float*)d_out;

    const int eb_blocks = (N_EDGES + 255) / 256;

    // CSR build (once; reused by all layers)
    hipMemsetAsync(cursor, 0, N_NODES * sizeof(int), stream);
    k_hist<<<eb_blocks, 256, 0, stream>>>(ei, cursor);
    k_scan<<<1, 1024, 0, stream>>>(cursor, row_ptr, cursor);
    k_scatter<<<eb_blocks, 256, 0, stream>>>(ei, (const float4*)ea, cursor, srcs, ea_s);

    k_inproj<<<1024, 256, 0, stream>>>(x, in_w, in_b, h0);

    float* hin = h0;
    float* hout = h1;
    for (int l = 0; l < 4; ++l) {
        k_aggr<<<N_NODES / 4, 256, 0, stream>>>(hin, zbuf, row_ptr, srcs, ea_s,
                                                edge_w + l * 4 * HIDDEN,
                                                edge_b + l * HIDDEN);
        k_mlp<<<2048, 256, 0, stream>>>(zbuf, hout,
                                        mlp_w1 + l * HIDDEN * 128,
                                        mlp_b1 + l * 128,
                                        mlp_w2 + l * 128 * HIDDEN,
                                        mlp_b2 + l * HIDDEN,
                                        ln_g + l * HIDDEN,
                                        ln_b + l * HIDDEN);
        float* t = hin; hin = hout; hout = t;
    }

    hipMemsetAsync(g, 0, HIDDEN * sizeof(float), stream);
    k_pool<<<256, 256, 0, stream>>>(hin, g);
    k_reg<<<1, 64, 0, stream>>>(g, reg_w1, reg_b1, reg_w2, reg_b2, outf);
}

// Round 4
// 484.680 us; speedup vs baseline: 2.3816x; 1.6941x over previous
//
#include <hip/hip_runtime.h>

#define N_NODES 50000
#define N_EDGES 800000
#define NODE_FEAT 176
#define HIDDEN 64
#define LN_EPS 1e-5f

typedef short bf16x8 __attribute__((ext_vector_type(8)));
typedef float f32x4 __attribute__((ext_vector_type(4)));

__device__ __forceinline__ unsigned short f2bf(float f) {
    unsigned int u = __float_as_uint(f);
    u += 0x7FFFu + ((u >> 16) & 1u);  // round-to-nearest-even
    return (unsigned short)(u >> 16);
}
__device__ __forceinline__ float bf2f(unsigned short s) {
    return __uint_as_float(((unsigned int)s) << 16);
}
__device__ __forceinline__ float wave_sum64(float v) {
#pragma unroll
    for (int o = 32; o > 0; o >>= 1) v += __shfl_xor(v, o);
    return v;
}
__device__ __forceinline__ float sum16(float v) {
#pragma unroll
    for (int o = 8; o > 0; o >>= 1) v += __shfl_xor(v, o);
    return v;
}

// ---------------- weight prep: bf16 MFMA B-fragment swizzle ----------------
// frag element order: [slice s][ntile j][lane][r] ; value = W[k][n],
// k = s*32 + (lane>>4)*8 + r, n = 16*j + (lane&15)
__global__ __launch_bounds__(256) void k_wprep(const float* __restrict__ in_w,
                                               const float* __restrict__ w1,
                                               const float* __restrict__ w2,
                                               unsigned short* __restrict__ fin,
                                               unsigned short* __restrict__ f1,
                                               unsigned short* __restrict__ f2) {
    int t = blockIdx.x * 256 + threadIdx.x;
    if (t < 12288) {  // in_w: [176->192 pad][64], 6 slices x 4 ntiles
        int e = t;
        int r = e & 7, lane = (e >> 3) & 63, j = (e >> 9) & 3, s = e >> 11;
        int k = s * 32 + ((lane >> 4) << 3) + r;
        int n = (j << 4) + (lane & 15);
        fin[e] = (k < NODE_FEAT) ? f2bf(in_w[k * 64 + n]) : (unsigned short)0;
    } else if (t < 12288 + 32768) {  // w1: 4 layers x [64][128], 2 slices x 8 ntiles
        int e = t - 12288;
        int L = e >> 13, e2 = e & 8191;
        int r = e2 & 7, lane = (e2 >> 3) & 63, j = (e2 >> 9) & 7, s = (e2 >> 12) & 1;
        int k = s * 32 + ((lane >> 4) << 3) + r;
        int n = (j << 4) + (lane & 15);
        f1[e] = f2bf(w1[L * 8192 + k * 128 + n]);
    } else {  // w2: 4 layers x [128][64], 4 slices x 4 ntiles
        int e = t - 45056;
        int L = e >> 13, e2 = e & 8191;
        int r = e2 & 7, lane = (e2 >> 3) & 63, j = (e2 >> 9) & 3, s = (e2 >> 11) & 3;
        int k = s * 32 + ((lane >> 4) << 3) + r;
        int n = (j << 4) + (lane & 15);
        f2[e] = f2bf(w2[L * 8192 + k * 64 + n]);
    }
}

// ---------------- input projection via MFMA ----------------
__global__ __launch_bounds__(256) void k_inproj_mfma(const float* __restrict__ x,
                                                     const unsigned short* __restrict__ wfrag,
                                                     const float* __restrict__ in_b,
                                                     float* __restrict__ h,
                                                     unsigned short* __restrict__ hb) {
    __shared__ unsigned short lw[12288];  // 24 KB
    const int tid = threadIdx.x;
    {
        const bf16x8* src = (const bf16x8*)wfrag;
        bf16x8* dst = (bf16x8*)lw;
        for (int i = tid; i < 1536; i += 256) dst[i] = src[i];
    }
    __syncthreads();
    const int wv = tid >> 6, lane = tid & 63;
    const int lrow = lane & 15, lgrp = lane >> 4;
    float ib[4];
#pragma unroll
    for (int j = 0; j < 4; ++j) ib[j] = in_b[16 * j + lrow];
    const int nwaves = gridDim.x * 4;
    for (int tile = blockIdx.x * 4 + wv; tile < 3125; tile += nwaves) {
        const int m0 = tile * 16;
        f32x4 acc[4];
#pragma unroll
        for (int j = 0; j < 4; ++j) acc[j] = (f32x4){ib[j], ib[j], ib[j], ib[j]};
#pragma unroll
        for (int s = 0; s < 6; ++s) {
            const int kbase = s * 32 + lgrp * 8;
            bf16x8 a;
            if (kbase < NODE_FEAT) {
                const float* p = x + (size_t)(m0 + lrow) * NODE_FEAT + kbase;
                float4 fa = *(const float4*)p;
                float4 fb = *(const float4*)(p + 4);
                a[0] = (short)f2bf(fa.x); a[1] = (short)f2bf(fa.y);
                a[2] = (short)f2bf(fa.z); a[3] = (short)f2bf(fa.w);
                a[4] = (short)f2bf(fb.x); a[5] = (short)f2bf(fb.y);
                a[6] = (short)f2bf(fb.z); a[7] = (short)f2bf(fb.w);
            } else {
                a = (bf16x8){0, 0, 0, 0, 0, 0, 0, 0};
            }
#pragma unroll
            for (int j = 0; j < 4; ++j) {
                bf16x8 b = *(const bf16x8*)&lw[((s * 4 + j) * 64 + lane) * 8];
                acc[j] = __builtin_amdgcn_mfma_f32_16x16x32_bf16(a, b, acc[j], 0, 0, 0);
            }
        }
#pragma unroll
        for (int j = 0; j < 4; ++j) {
            const int col = 16 * j + lrow;
#pragma unroll
            for (int r = 0; r < 4; ++r) {
                const int node = m0 + lgrp * 4 + r;
                float v = acc[j][r];
                h[(size_t)node * 64 + col] = v;
                hb[(size_t)node * 64 + col] = f2bf(v);
            }
        }
    }
}

// ---------------- CSR build ----------------
__global__ __launch_bounds__(256) void k_hist(const int* __restrict__ ei,
                                              int* __restrict__ cnt) {
    int e = blockIdx.x * 256 + threadIdx.x;
    if (e < N_EDGES) atomicAdd(&cnt[ei[N_EDGES + e]], 1);
}

__global__ __launch_bounds__(1024) void k_scan(const int* __restrict__ cnt,
                                               int* __restrict__ row_ptr,
                                               int* __restrict__ cursor) {
    __shared__ int part[1024];
    const int t = threadIdx.x;
    const int beg = t * 49;
    const int end = min(beg + 49, N_NODES);
    int s = 0;
    for (int i = beg; i < end; ++i) s += cnt[i];
    part[t] = s;
    __syncthreads();
    for (int off = 1; off < 1024; off <<= 1) {
        int v = (t >= off) ? part[t - off] : 0;
        __syncthreads();
        part[t] += v;
        __syncthreads();
    }
    int run = (t == 0) ? 0 : part[t - 1];
    for (int i = beg; i < end; ++i) {
        row_ptr[i] = run;
        cursor[i] = run;
        run += cnt[i];
    }
    if (t == 1023) row_ptr[N_NODES] = part[1023];
}

__global__ __launch_bounds__(256) void k_scatter(const int* __restrict__ ei,
                                                 const float4* __restrict__ ea,
                                                 int* __restrict__ cursor,
                                                 int* __restrict__ srcs,
                                                 float4* __restrict__ ea_s) {
    int e = blockIdx.x * 256 + threadIdx.x;
    if (e >= N_EDGES) return;
    int d = ei[N_EDGES + e];
    int pos = atomicAdd(&cursor[d], 1);
    srcs[pos] = ei[e];
    ea_s[pos] = ea[e];
}

// ---------------- gather + aggregate (bf16 gathers, fp32 accum) ----------------
__global__ __launch_bounds__(256) void k_aggr(const float* __restrict__ h_in,
                                              const unsigned short* __restrict__ hb_in,
                                              float* __restrict__ z,
                                              const int* __restrict__ row_ptr,
                                              const int* __restrict__ srcs,
                                              const float4* __restrict__ ea_s,
                                              const float* __restrict__ ew,
                                              const float* __restrict__ eb) {
    const int wv = threadIdx.x >> 6, lane = threadIdx.x & 63;
    const int node = blockIdx.x * 4 + wv;  // 12500*4 = 50000 exact
    const float ew0 = ew[0 * 64 + lane], ew1 = ew[1 * 64 + lane];
    const float ew2 = ew[2 * 64 + lane], ew3 = ew[3 * 64 + lane];
    const float ebl = eb[lane];
    const int beg = row_ptr[node];
    const int end = row_ptr[node + 1];
    float acc = h_in[(size_t)node * 64 + lane];
    int i = beg;
    const int n8 = beg + ((end - beg) & ~7);
    for (; i < n8; i += 8) {
        int s[8];
        float4 a[8];
        float gg[8];
#pragma unroll
        for (int t = 0; t < 8; ++t) s[t] = srcs[i + t];
#pragma unroll
        for (int t = 0; t < 8; ++t) a[t] = ea_s[i + t];
#pragma unroll
        for (int t = 0; t < 8; ++t) gg[t] = bf2f(hb_in[(size_t)s[t] * 64 + lane]);
#pragma unroll
        for (int t = 0; t < 8; ++t) {
            float v = fmaf(a[t].x, ew0, fmaf(a[t].y, ew1, fmaf(a[t].z, ew2, fmaf(a[t].w, ew3, ebl))));
            acc += fmaxf(v + gg[t], 0.0f);
        }
    }
    for (; i < end; ++i) {
        int s0 = srcs[i];
        float4 a0 = ea_s[i];
        float g0 = bf2f(hb_in[(size_t)s0 * 64 + lane]);
        float v = fmaf(a0.x, ew0, fmaf(a0.y, ew1, fmaf(a0.z, ew2, fmaf(a0.w, ew3, ebl))));
        acc += fmaxf(v + g0, 0.0f);
    }
    z[(size_t)node * 64 + lane] = acc;
}

// ---------------- MLP + LN + relu via MFMA (in-place on z) ----------------
__global__ __launch_bounds__(256) void k_mlp_mfma(float* __restrict__ z,  // in: z, out: h
                                                  unsigned short* __restrict__ hb_out,
                                                  const unsigned short* __restrict__ f1,
                                                  const unsigned short* __restrict__ f2,
                                                  const float* __restrict__ b1,
                                                  const float* __restrict__ b2,
                                                  const float* __restrict__ lng,
                                                  const float* __restrict__ lnb) {
    __shared__ unsigned short w1f[8192];     // 16 KB
    __shared__ unsigned short w2f[8192];     // 16 KB
    __shared__ unsigned short z1s[4][2048];  // 16 KB, per-wave swizzled scratch
    const int tid = threadIdx.x;
    {
        const bf16x8* s1 = (const bf16x8*)f1;
        const bf16x8* s2 = (const bf16x8*)f2;
        bf16x8* d1 = (bf16x8*)w1f;
        bf16x8* d2 = (bf16x8*)w2f;
        for (int i = tid; i < 1024; i += 256) { d1[i] = s1[i]; d2[i] = s2[i]; }
    }
    __syncthreads();
    const int wv = tid >> 6, lane = tid & 63;
    const int lrow = lane & 15, lgrp = lane >> 4;
    unsigned short* zs = z1s[wv];
    float bb1[8], bb2[4], g4[4], be4[4];
#pragma unroll
    for (int j = 0; j < 8; ++j) bb1[j] = b1[16 * j + lrow];
#pragma unroll
    for (int j = 0; j < 4; ++j) {
        bb2[j] = b2[16 * j + lrow];
        g4[j] = lng[16 * j + lrow];
        be4[j] = lnb[16 * j + lrow];
    }
    const int nwaves = gridDim.x * 4;
    for (int tile = blockIdx.x * 4 + wv; tile < 3125; tile += nwaves) {
        const int m0 = tile * 16;
        // GEMM1: [16x64] @ [64x128]
        f32x4 acc1[8];
#pragma unroll
        for (int j = 0; j < 8; ++j) acc1[j] = (f32x4){bb1[j], bb1[j], bb1[j], bb1[j]};
#pragma unroll
        for (int s = 0; s < 2; ++s) {
            const int kbase = s * 32 + lgrp * 8;
            const float* p = z + (size_t)(m0 + lrow) * 64 + kbase;
            float4 fa = *(const float4*)p;
            float4 fb = *(const float4*)(p + 4);
            bf16x8 a;
            a[0] = (short)f2bf(fa.x); a[1] = (short)f2bf(fa.y);
            a[2] = (short)f2bf(fa.z); a[3] = (short)f2bf(fa.w);
            a[4] = (short)f2bf(fb.x); a[5] = (short)f2bf(fb.y);
            a[6] = (short)f2bf(fb.z); a[7] = (short)f2bf(fb.w);
#pragma unroll
            for (int j = 0; j < 8; ++j) {
                bf16x8 b = *(const bf16x8*)&w1f[((s * 8 + j) * 64 + lane) * 8];
                acc1[j] = __builtin_amdgcn_mfma_f32_16x16x32_bf16(a, b, acc1[j], 0, 0, 0);
            }
        }
        // relu -> bf16 -> swizzled LDS [16 rows][128 cols]
#pragma unroll
        for (int j = 0; j < 8; ++j) {
            const int col = 16 * j + lrow;
#pragma unroll
            for (int r = 0; r < 4; ++r) {
                const int row = lgrp * 4 + r;
                const int idx = (row * 128 + col) ^ ((row & 7) << 3);
                zs[idx] = f2bf(fmaxf(acc1[j][r], 0.0f));
            }
        }
        // GEMM2: [16x128] @ [128x64]  (per-wave scratch, no barrier needed)
        f32x4 acc2[4];
#pragma unroll
        for (int j = 0; j < 4; ++j) acc2[j] = (f32x4){bb2[j], bb2[j], bb2[j], bb2[j]};
#pragma unroll
        for (int s = 0; s < 4; ++s) {
            const int kbase = s * 32 + lgrp * 8;
            const int idx = (lrow * 128 + kbase) ^ ((lrow & 7) << 3);
            bf16x8 a = *(const bf16x8*)&zs[idx];
#pragma unroll
            for (int j = 0; j < 4; ++j) {
                bf16x8 b = *(const bf16x8*)&w2f[((s * 4 + j) * 64 + lane) * 8];
                acc2[j] = __builtin_amdgcn_mfma_f32_16x16x32_bf16(a, b, acc2[j], 0, 0, 0);
            }
        }
        // LayerNorm + relu per row, store h (fp32) + hb (bf16)
#pragma unroll
        for (int r = 0; r < 4; ++r) {
            float sum = acc2[0][r] + acc2[1][r] + acc2[2][r] + acc2[3][r];
            sum = sum16(sum);
            const float mu = sum * (1.0f / 64.0f);
            float sq = 0.0f;
#pragma unroll
            for (int j = 0; j < 4; ++j) {
                float d = acc2[j][r] - mu;
                sq = fmaf(d, d, sq);
            }
            sq = sum16(sq);
            const float rstd = rsqrtf(sq * (1.0f / 64.0f) + LN_EPS);
            const int node = m0 + lgrp * 4 + r;
#pragma unroll
            for (int j = 0; j < 4; ++j) {
                const int col = 16 * j + lrow;
                float d = acc2[j][r] - mu;
                float hn = fmaxf(fmaf(g4[j] * d, rstd, be4[j]), 0.0f);
                z[(size_t)node * 64 + col] = hn;
                hb_out[(size_t)node * 64 + col] = f2bf(hn);
            }
        }
    }
}

// ---------------- pool + regressor ----------------
__global__ __launch_bounds__(256) void k_pool(const float* __restrict__ h,
                                              float* __restrict__ g) {
    __shared__ float red[256];
    const int tid = threadIdx.x;
    const int lane = tid & 63;
    float part = 0.0f;
    for (int i = blockIdx.x * 4 + (tid >> 6); i < N_NODES; i += gridDim.x * 4)
        part += h[(size_t)i * 64 + lane];
    red[tid] = part;
    __syncthreads();
    if (tid < 64) {
        float s = red[tid] + red[tid + 64] + red[tid + 128] + red[tid + 192];
        atomicAdd(&g[tid], s);
    }
}

__global__ __launch_bounds__(64) void k_reg(const float* __restrict__ g,
                                            const float* __restrict__ w1,
                                            const float* __restrict__ b1,
                                            const float* __restrict__ w2,
                                            const float* __restrict__ b2,
                                            float* __restrict__ out) {
    const int j = threadIdx.x;
    const int jm = j & 31;
    float acc = b1[jm];
#pragma unroll 8
    for (int k = 0; k < 64; ++k) {
        float gk = g[k];
        acc = fmaf(gk, w1[k * 32 + jm], acc);
    }
    float contrib = (j < 32) ? fmaxf(acc, 0.0f) * w2[jm] : 0.0f;
    float s = wave_sum64(contrib);
    if (j == 0) out[0] = s + b2[0];
}

extern "C" void kernel_launch(void* const* d_in, const int* in_sizes, int n_in,
                              void* d_out, int out_size, void* d_ws, size_t ws_size,
                              hipStream_t stream) {
    const float* x      = (const float*)d_in[0];
    const int*   ei     = (const int*)d_in[1];
    const float* ea     = (const float*)d_in[2];
    const float* in_w   = (const float*)d_in[3];
    const float* in_b   = (const float*)d_in[4];
    const float* edge_w = (const float*)d_in[5];
    const float* edge_b = (const float*)d_in[6];
    const float* mlp_w1 = (const float*)d_in[7];
    const float* mlp_b1 = (const float*)d_in[8];
    const float* mlp_w2 = (const float*)d_in[9];
    const float* mlp_b2 = (const float*)d_in[10];
    const float* ln_g   = (const float*)d_in[11];
    const float* ln_b   = (const float*)d_in[12];
    const float* reg_w1 = (const float*)d_in[13];
    const float* reg_b1 = (const float*)d_in[14];
    const float* reg_w2 = (const float*)d_in[15];
    const float* reg_b2 = (const float*)d_in[16];

    char* ws = (char*)d_ws;
    float*          h0      = (float*)ws;          ws += (size_t)N_NODES * 64 * 4;
    float*          h1      = (float*)ws;          ws += (size_t)N_NODES * 64 * 4;
    float4*         ea_s    = (float4*)ws;         ws += (size_t)N_EDGES * 16;
    unsigned short* hb0     = (unsigned short*)ws; ws += (size_t)N_NODES * 64 * 2;
    unsigned short* hb1     = (unsigned short*)ws; ws += (size_t)N_NODES * 64 * 2;
    unsigned short* fin     = (unsigned short*)ws; ws += 12288 * 2;
    unsigned short* f1      = (unsigned short*)ws; ws += 32768 * 2;
    unsigned short* f2      = (unsigned short*)ws; ws += 32768 * 2;
    int*            srcs    = (int*)ws;            ws += (size_t)N_EDGES * 4;
    int*            row_ptr = (int*)ws;            ws += (size_t)(N_NODES + 1) * 4;
    int*            cursor  = (int*)ws;            ws += (size_t)N_NODES * 4;
    float*          g       = (float*)ws;          ws += 64 * 4;
    float*          outf    = (float*)d_out;

    const int eb_blocks = (N_EDGES + 255) / 256;

    k_wprep<<<304, 256, 0, stream>>>(in_w, mlp_w1, mlp_w2, fin, f1, f2);

    hipMemsetAsync(cursor, 0, N_NODES * sizeof(int), stream);
    k_hist<<<eb_blocks, 256, 0, stream>>>(ei, cursor);
    k_scan<<<1, 1024, 0, stream>>>(cursor, row_ptr, cursor);
    k_scatter<<<eb_blocks, 256, 0, stream>>>(ei, (const float4*)ea, cursor, srcs, ea_s);

    k_inproj_mfma<<<256, 256, 0, stream>>>(x, fin, in_b, h0, hb0);

    float* hA = h0;
    float* hB = h1;
    unsigned short* hbA = hb0;
    unsigned short* hbB = hb1;
    for (int l = 0; l < 4; ++l) {
        k_aggr<<<N_NODES / 4, 256, 0, stream>>>(hA, hbA, hB, row_ptr, srcs, ea_s,
                                                edge_w + l * 4 * 64,
                                                edge_b + l * 64);
        k_mlp_mfma<<<256, 256, 0, stream>>>(hB, hbB,
                                            f1 + l * 8192, f2 + l * 8192,
                                            mlp_b1 + l * 128, mlp_b2 + l * 64,
                                            ln_g + l * 64, ln_b + l * 64);
        float* t = hA; hA = hB; hB = t;
        unsigned short* tb = hbA; hbA = hbB; hbB = tb;
    }

    hipMemsetAsync(g, 0, 64 * sizeof(float), stream);
    k_pool<<<256, 256, 0, stream>>>(hA, g);
    k_reg<<<1, 64, 0, stream>>>(g, reg_w1, reg_b1, reg_w2, reg_b2, outf);
}

// Round 5
// 386.297 us; speedup vs baseline: 2.9882x; 1.2547x over previous
//
#include <hip/hip_runtime.h>

#define N_NODES 50000
#define N_EDGES 800000
#define NODE_FEAT 176
#define HIDDEN 64
#define LN_EPS 1e-5f
#define SCAN_NB 49  // ceil(50000/1024)

typedef short bf16x8 __attribute__((ext_vector_type(8)));
typedef float f32x4 __attribute__((ext_vector_type(4)));

__device__ __forceinline__ unsigned short f2bf(float f) {
    unsigned int u = __float_as_uint(f);
    u += 0x7FFFu + ((u >> 16) & 1u);  // round-to-nearest-even
    return (unsigned short)(u >> 16);
}
__device__ __forceinline__ float bf2f(unsigned short s) {
    return __uint_as_float(((unsigned int)s) << 16);
}
__device__ __forceinline__ float wave_sum64(float v) {
#pragma unroll
    for (int o = 32; o > 0; o >>= 1) v += __shfl_xor(v, o);
    return v;
}
__device__ __forceinline__ float sum16(float v) {
#pragma unroll
    for (int o = 8; o > 0; o >>= 1) v += __shfl_xor(v, o);
    return v;
}

// ---------------- weight prep: bf16 MFMA B-fragment swizzle ----------------
__global__ __launch_bounds__(256) void k_wprep(const float* __restrict__ in_w,
                                               const float* __restrict__ w1,
                                               const float* __restrict__ w2,
                                               unsigned short* __restrict__ fin,
                                               unsigned short* __restrict__ f1,
                                               unsigned short* __restrict__ f2) {
    int t = blockIdx.x * 256 + threadIdx.x;
    if (t < 12288) {  // in_w: [176->192 pad][64], 6 slices x 4 ntiles
        int e = t;
        int r = e & 7, lane = (e >> 3) & 63, j = (e >> 9) & 3, s = e >> 11;
        int k = s * 32 + ((lane >> 4) << 3) + r;
        int n = (j << 4) + (lane & 15);
        fin[e] = (k < NODE_FEAT) ? f2bf(in_w[k * 64 + n]) : (unsigned short)0;
    } else if (t < 12288 + 32768) {  // w1: 4 layers x [64][128]
        int e = t - 12288;
        int L = e >> 13, e2 = e & 8191;
        int r = e2 & 7, lane = (e2 >> 3) & 63, j = (e2 >> 9) & 7, s = (e2 >> 12) & 1;
        int k = s * 32 + ((lane >> 4) << 3) + r;
        int n = (j << 4) + (lane & 15);
        f1[e] = f2bf(w1[L * 8192 + k * 128 + n]);
    } else {  // w2: 4 layers x [128][64]
        int e = t - 45056;
        int L = e >> 13, e2 = e & 8191;
        int r = e2 & 7, lane = (e2 >> 3) & 63, j = (e2 >> 9) & 3, s = (e2 >> 11) & 3;
        int k = s * 32 + ((lane >> 4) << 3) + r;
        int n = (j << 4) + (lane & 15);
        f2[e] = f2bf(w2[L * 8192 + k * 64 + n]);
    }
}

// ---------------- input projection via MFMA ----------------
__global__ __launch_bounds__(256) void k_inproj_mfma(const float* __restrict__ x,
                                                     const unsigned short* __restrict__ wfrag,
                                                     const float* __restrict__ in_b,
                                                     float* __restrict__ h,
                                                     unsigned short* __restrict__ hb) {
    __shared__ unsigned short lw[12288];  // 24 KB
    const int tid = threadIdx.x;
    {
        const bf16x8* src = (const bf16x8*)wfrag;
        bf16x8* dst = (bf16x8*)lw;
        for (int i = tid; i < 1536; i += 256) dst[i] = src[i];
    }
    __syncthreads();
    const int wv = tid >> 6, lane = tid & 63;
    const int lrow = lane & 15, lgrp = lane >> 4;
    float ib[4];
#pragma unroll
    for (int j = 0; j < 4; ++j) ib[j] = in_b[16 * j + lrow];
    const int nwaves = gridDim.x * 4;
    for (int tile = blockIdx.x * 4 + wv; tile < 3125; tile += nwaves) {
        const int m0 = tile * 16;
        f32x4 acc[4];
#pragma unroll
        for (int j = 0; j < 4; ++j) acc[j] = (f32x4){ib[j], ib[j], ib[j], ib[j]};
#pragma unroll
        for (int s = 0; s < 6; ++s) {
            const int kbase = s * 32 + lgrp * 8;
            bf16x8 a;
            if (kbase < NODE_FEAT) {
                const float* p = x + (size_t)(m0 + lrow) * NODE_FEAT + kbase;
                float4 fa = *(const float4*)p;
                float4 fb = *(const float4*)(p + 4);
                a[0] = (short)f2bf(fa.x); a[1] = (short)f2bf(fa.y);
                a[2] = (short)f2bf(fa.z); a[3] = (short)f2bf(fa.w);
                a[4] = (short)f2bf(fb.x); a[5] = (short)f2bf(fb.y);
                a[6] = (short)f2bf(fb.z); a[7] = (short)f2bf(fb.w);
            } else {
                a = (bf16x8){0, 0, 0, 0, 0, 0, 0, 0};
            }
#pragma unroll
            for (int j = 0; j < 4; ++j) {
                bf16x8 b = *(const bf16x8*)&lw[((s * 4 + j) * 64 + lane) * 8];
                acc[j] = __builtin_amdgcn_mfma_f32_16x16x32_bf16(a, b, acc[j], 0, 0, 0);
            }
        }
#pragma unroll
        for (int j = 0; j < 4; ++j) {
            const int col = 16 * j + lrow;
#pragma unroll
            for (int r = 0; r < 4; ++r) {
                const int node = m0 + lgrp * 4 + r;
                float v = acc[j][r];
                h[(size_t)node * 64 + col] = v;
                hb[(size_t)node * 64 + col] = f2bf(v);
            }
        }
    }
}

// ---------------- CSR build ----------------
__global__ __launch_bounds__(256) void k_hist(const int* __restrict__ ei,
                                              int* __restrict__ cnt) {
    int e = blockIdx.x * 256 + threadIdx.x;
    if (e < N_EDGES) atomicAdd(&cnt[ei[N_EDGES + e]], 1);
}

// parallel 3-phase scan of cnt[50000] -> row_ptr / cursor
__global__ __launch_bounds__(256) void k_scan_part(const int* __restrict__ cnt,
                                                   int* __restrict__ blksum) {
    const int b = blockIdx.x, t = threadIdx.x;
    const int base = b * 1024 + t * 4;
    int s = 0;
#pragma unroll
    for (int i = 0; i < 4; ++i) {
        int idx = base + i;
        if (idx < N_NODES) s += cnt[idx];
    }
#pragma unroll
    for (int o = 32; o > 0; o >>= 1) s += __shfl_xor(s, o);
    __shared__ int wt[4];
    if ((t & 63) == 0) wt[t >> 6] = s;
    __syncthreads();
    if (t == 0) blksum[b] = wt[0] + wt[1] + wt[2] + wt[3];
}

__global__ __launch_bounds__(64) void k_scan_top(const int* __restrict__ blksum,
                                                 int* __restrict__ blkoff,
                                                 int* __restrict__ row_last) {
    const int t = threadIdx.x;
    int v = (t < SCAN_NB) ? blksum[t] : 0;
    int incl = v;
#pragma unroll
    for (int o = 1; o < 64; o <<= 1) {
        int u = __shfl_up(incl, o);
        if (t >= o) incl += u;
    }
    if (t < SCAN_NB) blkoff[t] = incl - v;
    if (t == 63) row_last[0] = incl;
}

__global__ __launch_bounds__(256) void k_scan_add(const int* __restrict__ cnt,
                                                  const int* __restrict__ blkoff,
                                                  int* __restrict__ row_ptr,
                                                  int* __restrict__ cursor) {
    const int b = blockIdx.x, t = threadIdx.x;
    const int base = b * 1024 + t * 4;
    int c[4];
    int tsum = 0;
#pragma unroll
    for (int i = 0; i < 4; ++i) {
        int idx = base + i;
        c[i] = (idx < N_NODES) ? cnt[idx] : 0;
        tsum += c[i];
    }
    int incl = tsum;
#pragma unroll
    for (int o = 1; o < 64; o <<= 1) {
        int u = __shfl_up(incl, o);
        if ((t & 63) >= o) incl += u;
    }
    __shared__ int wt[4];
    const int wv = t >> 6;
    if ((t & 63) == 63) wt[wv] = incl;
    __syncthreads();
    int run = blkoff[b] + (incl - tsum);
    for (int w = 0; w < wv; ++w) run += wt[w];
#pragma unroll
    for (int i = 0; i < 4; ++i) {
        int idx = base + i;
        if (idx < N_NODES) { row_ptr[idx] = run; cursor[idx] = run; }
        run += c[i];
    }
}

__global__ __launch_bounds__(256) void k_scatter(const int* __restrict__ ei,
                                                 const float4* __restrict__ ea,
                                                 int* __restrict__ cursor,
                                                 int* __restrict__ srcs,
                                                 float4* __restrict__ ea_s) {
    int e = blockIdx.x * 256 + threadIdx.x;
    if (e >= N_EDGES) return;
    int d = ei[N_EDGES + e];
    int pos = atomicAdd(&cursor[d], 1);
    srcs[pos] = ei[e];
    ea_s[pos] = ea[e];
}

// ---------------- gather + aggregate (bf16 gathers, fp32 accum) ----------------
__global__ __launch_bounds__(256) void k_aggr(const float* __restrict__ h_in,
                                              const unsigned short* __restrict__ hb_in,
                                              float* __restrict__ z,
                                              const int* __restrict__ row_ptr,
                                              const int* __restrict__ srcs,
                                              const float4* __restrict__ ea_s,
                                              const float* __restrict__ ew,
                                              const float* __restrict__ eb) {
    const int wv = threadIdx.x >> 6, lane = threadIdx.x & 63;
    const int node = blockIdx.x * 4 + wv;  // 12500*4 = 50000 exact
    const float ew0 = ew[0 * 64 + lane], ew1 = ew[1 * 64 + lane];
    const float ew2 = ew[2 * 64 + lane], ew3 = ew[3 * 64 + lane];
    const float ebl = eb[lane];
    const int beg = row_ptr[node];
    const int end = row_ptr[node + 1];
    float acc = h_in[(size_t)node * 64 + lane];
    int i = beg;
    const int n8 = beg + ((end - beg) & ~7);
    for (; i < n8; i += 8) {
        int s[8];
        float4 a[8];
        float gg[8];
#pragma unroll
        for (int t = 0; t < 8; ++t) s[t] = srcs[i + t];
#pragma unroll
        for (int t = 0; t < 8; ++t) a[t] = ea_s[i + t];
#pragma unroll
        for (int t = 0; t < 8; ++t) gg[t] = bf2f(hb_in[(size_t)s[t] * 64 + lane]);
#pragma unroll
        for (int t = 0; t < 8; ++t) {
            float v = fmaf(a[t].x, ew0, fmaf(a[t].y, ew1, fmaf(a[t].z, ew2, fmaf(a[t].w, ew3, ebl))));
            acc += fmaxf(v + gg[t], 0.0f);
        }
    }
    for (; i < end; ++i) {
        int s0 = srcs[i];
        float4 a0 = ea_s[i];
        float g0 = bf2f(hb_in[(size_t)s0 * 64 + lane]);
        float v = fmaf(a0.x, ew0, fmaf(a0.y, ew1, fmaf(a0.z, ew2, fmaf(a0.w, ew3, ebl))));
        acc += fmaxf(v + g0, 0.0f);
    }
    z[(size_t)node * 64 + lane] = acc;
}

// ---------------- MLP + LN + relu via MFMA (in-place on z) ----------------
__global__ __launch_bounds__(256) void k_mlp_mfma(float* __restrict__ z,  // in: z, out: h
                                                  unsigned short* __restrict__ hb_out,
                                                  const unsigned short* __restrict__ f1,
                                                  const unsigned short* __restrict__ f2,
                                                  const float* __restrict__ b1,
                                                  const float* __restrict__ b2,
                                                  const float* __restrict__ lng,
                                                  const float* __restrict__ lnb) {
    __shared__ unsigned short w1f[8192];     // 16 KB
    __shared__ unsigned short w2f[8192];     // 16 KB
    __shared__ unsigned short z1s[4][2048];  // 16 KB, per-wave swizzled scratch
    const int tid = threadIdx.x;
    {
        const bf16x8* s1 = (const bf16x8*)f1;
        const bf16x8* s2 = (const bf16x8*)f2;
        bf16x8* d1 = (bf16x8*)w1f;
        bf16x8* d2 = (bf16x8*)w2f;
        for (int i = tid; i < 1024; i += 256) { d1[i] = s1[i]; d2[i] = s2[i]; }
    }
    __syncthreads();
    const int wv = tid >> 6, lane = tid & 63;
    const int lrow = lane & 15, lgrp = lane >> 4;
    unsigned short* zs = z1s[wv];
    float bb1[8], bb2[4], g4[4], be4[4];
#pragma unroll
    for (int j = 0; j < 8; ++j) bb1[j] = b1[16 * j + lrow];
#pragma unroll
    for (int j = 0; j < 4; ++j) {
        bb2[j] = b2[16 * j + lrow];
        g4[j] = lng[16 * j + lrow];
        be4[j] = lnb[16 * j + lrow];
    }
    const int nwaves = gridDim.x * 4;
    for (int tile = blockIdx.x * 4 + wv; tile < 3125; tile += nwaves) {
        const int m0 = tile * 16;
        // GEMM1: [16x64] @ [64x128]
        f32x4 acc1[8];
#pragma unroll
        for (int j = 0; j < 8; ++j) acc1[j] = (f32x4){bb1[j], bb1[j], bb1[j], bb1[j]};
#pragma unroll
        for (int s = 0; s < 2; ++s) {
            const int kbase = s * 32 + lgrp * 8;
            const float* p = z + (size_t)(m0 + lrow) * 64 + kbase;
            float4 fa = *(const float4*)p;
            float4 fb = *(const float4*)(p + 4);
            bf16x8 a;
            a[0] = (short)f2bf(fa.x); a[1] = (short)f2bf(fa.y);
            a[2] = (short)f2bf(fa.z); a[3] = (short)f2bf(fa.w);
            a[4] = (short)f2bf(fb.x); a[5] = (short)f2bf(fb.y);
            a[6] = (short)f2bf(fb.z); a[7] = (short)f2bf(fb.w);
#pragma unroll
            for (int j = 0; j < 8; ++j) {
                bf16x8 b = *(const bf16x8*)&w1f[((s * 8 + j) * 64 + lane) * 8];
                acc1[j] = __builtin_amdgcn_mfma_f32_16x16x32_bf16(a, b, acc1[j], 0, 0, 0);
            }
        }
        // relu -> bf16 -> swizzled LDS [16 rows][128 cols]
#pragma unroll
        for (int j = 0; j < 8; ++j) {
            const int col = 16 * j + lrow;
#pragma unroll
            for (int r = 0; r < 4; ++r) {
                const int row = lgrp * 4 + r;
                const int idx = (row * 128 + col) ^ ((row & 7) << 3);
                zs[idx] = f2bf(fmaxf(acc1[j][r], 0.0f));
            }
        }
        // GEMM2: [16x128] @ [128x64]  (per-wave scratch, no barrier needed)
        f32x4 acc2[4];
#pragma unroll
        for (int j = 0; j < 4; ++j) acc2[j] = (f32x4){bb2[j], bb2[j], bb2[j], bb2[j]};
#pragma unroll
        for (int s = 0; s < 4; ++s) {
            const int kbase = s * 32 + lgrp * 8;
            const int idx = (lrow * 128 + kbase) ^ ((lrow & 7) << 3);
            bf16x8 a = *(const bf16x8*)&zs[idx];
#pragma unroll
            for (int j = 0; j < 4; ++j) {
                bf16x8 b = *(const bf16x8*)&w2f[((s * 4 + j) * 64 + lane) * 8];
                acc2[j] = __builtin_amdgcn_mfma_f32_16x16x32_bf16(a, b, acc2[j], 0, 0, 0);
            }
        }
        // LayerNorm + relu per row, store h (fp32) + hb (bf16)
#pragma unroll
        for (int r = 0; r < 4; ++r) {
            float sum = acc2[0][r] + acc2[1][r] + acc2[2][r] + acc2[3][r];
            sum = sum16(sum);
            const float mu = sum * (1.0f / 64.0f);
            float sq = 0.0f;
#pragma unroll
            for (int j = 0; j < 4; ++j) {
                float d = acc2[j][r] - mu;
                sq = fmaf(d, d, sq);
            }
            sq = sum16(sq);
            const float rstd = rsqrtf(sq * (1.0f / 64.0f) + LN_EPS);
            const int node = m0 + lgrp * 4 + r;
#pragma unroll
            for (int j = 0; j < 4; ++j) {
                const int col = 16 * j + lrow;
                float d = acc2[j][r] - mu;
                float hn = fmaxf(fmaf(g4[j] * d, rstd, be4[j]), 0.0f);
                z[(size_t)node * 64 + col] = hn;
                hb_out[(size_t)node * 64 + col] = f2bf(hn);
            }
        }
    }
}

// ---------------- pool + regressor ----------------
__global__ __launch_bounds__(256) void k_pool(const float* __restrict__ h,
                                              float* __restrict__ g) {
    __shared__ float red[256];
    const int tid = threadIdx.x;
    const int lane = tid & 63;
    float part = 0.0f;
    for (int i = blockIdx.x * 4 + (tid >> 6); i < N_NODES; i += gridDim.x * 4)
        part += h[(size_t)i * 64 + lane];
    red[tid] = part;
    __syncthreads();
    if (tid < 64) {
        float s = red[tid] + red[tid + 64] + red[tid + 128] + red[tid + 192];
        atomicAdd(&g[tid], s);
    }
}

__global__ __launch_bounds__(64) void k_reg(const float* __restrict__ g,
                                            const float* __restrict__ w1,
                                            const float* __restrict__ b1,
                                            const float* __restrict__ w2,
                                            const float* __restrict__ b2,
                                            float* __restrict__ out) {
    const int j = threadIdx.x;
    const int jm = j & 31;
    float acc = b1[jm];
#pragma unroll 8
    for (int k = 0; k < 64; ++k) {
        float gk = g[k];
        acc = fmaf(gk, w1[k * 32 + jm], acc);
    }
    float contrib = (j < 32) ? fmaxf(acc, 0.0f) * w2[jm] : 0.0f;
    float s = wave_sum64(contrib);
    if (j == 0) out[0] = s + b2[0];
}

extern "C" void kernel_launch(void* const* d_in, const int* in_sizes, int n_in,
                              void* d_out, int out_size, void* d_ws, size_t ws_size,
                              hipStream_t stream) {
    const float* x      = (const float*)d_in[0];
    const int*   ei     = (const int*)d_in[1];
    const float* ea     = (const float*)d_in[2];
    const float* in_w   = (const float*)d_in[3];
    const float* in_b   = (const float*)d_in[4];
    const float* edge_w = (const float*)d_in[5];
    const float* edge_b = (const float*)d_in[6];
    const float* mlp_w1 = (const float*)d_in[7];
    const float* mlp_b1 = (const float*)d_in[8];
    const float* mlp_w2 = (const float*)d_in[9];
    const float* mlp_b2 = (const float*)d_in[10];
    const float* ln_g   = (const float*)d_in[11];
    const float* ln_b   = (const float*)d_in[12];
    const float* reg_w1 = (const float*)d_in[13];
    const float* reg_b1 = (const float*)d_in[14];
    const float* reg_w2 = (const float*)d_in[15];
    const float* reg_b2 = (const float*)d_in[16];

    char* ws = (char*)d_ws;
    float*          h0      = (float*)ws;          ws += (size_t)N_NODES * 64 * 4;
    float*          h1      = (float*)ws;          ws += (size_t)N_NODES * 64 * 4;
    float4*         ea_s    = (float4*)ws;         ws += (size_t)N_EDGES * 16;
    unsigned short* hb0     = (unsigned short*)ws; ws += (size_t)N_NODES * 64 * 2;
    unsigned short* hb1     = (unsigned short*)ws; ws += (size_t)N_NODES * 64 * 2;
    unsigned short* fin     = (unsigned short*)ws; ws += 12288 * 2;
    unsigned short* f1      = (unsigned short*)ws; ws += 32768 * 2;
    unsigned short* f2      = (unsigned short*)ws; ws += 32768 * 2;
    int*            srcs    = (int*)ws;            ws += (size_t)N_EDGES * 4;
    int*            row_ptr = (int*)ws;            ws += (size_t)(N_NODES + 1) * 4;
    int*            cursor  = (int*)ws;            ws += (size_t)N_NODES * 4;
    int*            blksum  = (int*)ws;            ws += SCAN_NB * 4;
    int*            blkoff  = (int*)ws;            ws += SCAN_NB * 4;
    float*          g       = (float*)ws;          ws += 64 * 4;
    float*          outf    = (float*)d_out;

    const int eb_blocks = (N_EDGES + 255) / 256;

    k_wprep<<<304, 256, 0, stream>>>(in_w, mlp_w1, mlp_w2, fin, f1, f2);

    hipMemsetAsync(cursor, 0, N_NODES * sizeof(int), stream);
    k_hist<<<eb_blocks, 256, 0, stream>>>(ei, cursor);
    k_scan_part<<<SCAN_NB, 256, 0, stream>>>(cursor, blksum);
    k_scan_top<<<1, 64, 0, stream>>>(blksum, blkoff, row_ptr + N_NODES);
    k_scan_add<<<SCAN_NB, 256, 0, stream>>>(cursor, blkoff, row_ptr, cursor);
    k_scatter<<<eb_blocks, 256, 0, stream>>>(ei, (const float4*)ea, cursor, srcs, ea_s);

    k_inproj_mfma<<<256, 256, 0, stream>>>(x, fin, in_b, h0, hb0);

    float* hA = h0;
    float* hB = h1;
    unsigned short* hbA = hb0;
    unsigned short* hbB = hb1;
    for (int l = 0; l < 4; ++l) {
        k_aggr<<<N_NODES / 4, 256, 0, stream>>>(hA, hbA, hB, row_ptr, srcs, ea_s,
                                                edge_w + l * 4 * 64,
                                                edge_b + l * 64);
        k_mlp_mfma<<<256, 256, 0, stream>>>(hB, hbB,
                                            f1 + l * 8192, f2 + l * 8192,
                                            mlp_b1 + l * 128, mlp_b2 + l * 64,
                                            ln_g + l * 64, ln_b + l * 64);
        float* t = hA; hA = hB; hB = t;
        unsigned short* tb = hbA; hbA = hbB; hbB = tb;
    }

    hipMemsetAsync(g, 0, 64 * sizeof(float), stream);
    k_pool<<<256, 256, 0, stream>>>(hA, g);
    k_reg<<<1, 64, 0, stream>>>(g, reg_w1, reg_b1, reg_w2, reg_b2, outf);
}

// Round 6
// 337.280 us; speedup vs baseline: 3.4225x; 1.1453x over previous
//
#include <hip/hip_runtime.h>

#define N_NODES 50000
#define N_EDGES 800000
#define NODE_FEAT 176
#define HIDDEN 64
#define LN_EPS 1e-5f
#define SCAN_NB 49  // ceil(50000/1024)

typedef short bf16x8 __attribute__((ext_vector_type(8)));
typedef float f32x4 __attribute__((ext_vector_type(4)));

__device__ __forceinline__ unsigned short f2bf(float f) {
    unsigned int u = __float_as_uint(f);
    u += 0x7FFFu + ((u >> 16) & 1u);  // round-to-nearest-even
    return (unsigned short)(u >> 16);
}
__device__ __forceinline__ float bf2f(unsigned short s) {
    return __uint_as_float(((unsigned int)s) << 16);
}
__device__ __forceinline__ float wave_sum64(float v) {
#pragma unroll
    for (int o = 32; o > 0; o >>= 1) v += __shfl_xor(v, o);
    return v;
}
__device__ __forceinline__ float sum16(float v) {
#pragma unroll
    for (int o = 8; o > 0; o >>= 1) v += __shfl_xor(v, o);
    return v;
}

// ---------------- weight prep: bf16 MFMA B-fragment swizzle ----------------
__global__ __launch_bounds__(256) void k_wprep(const float* __restrict__ in_w,
                                               const float* __restrict__ w1,
                                               const float* __restrict__ w2,
                                               unsigned short* __restrict__ fin,
                                               unsigned short* __restrict__ f1,
                                               unsigned short* __restrict__ f2) {
    int t = blockIdx.x * 256 + threadIdx.x;
    if (t < 12288) {  // in_w: [176->192 pad][64], 6 slices x 4 ntiles
        int e = t;
        int r = e & 7, lane = (e >> 3) & 63, j = (e >> 9) & 3, s = e >> 11;
        int k = s * 32 + ((lane >> 4) << 3) + r;
        int n = (j << 4) + (lane & 15);
        fin[e] = (k < NODE_FEAT) ? f2bf(in_w[k * 64 + n]) : (unsigned short)0;
    } else if (t < 12288 + 32768) {  // w1: 4 layers x [64][128]
        int e = t - 12288;
        int L = e >> 13, e2 = e & 8191;
        int r = e2 & 7, lane = (e2 >> 3) & 63, j = (e2 >> 9) & 7, s = (e2 >> 12) & 1;
        int k = s * 32 + ((lane >> 4) << 3) + r;
        int n = (j << 4) + (lane & 15);
        f1[e] = f2bf(w1[L * 8192 + k * 128 + n]);
    } else {  // w2: 4 layers x [128][64]
        int e = t - 45056;
        int L = e >> 13, e2 = e & 8191;
        int r = e2 & 7, lane = (e2 >> 3) & 63, j = (e2 >> 9) & 3, s = (e2 >> 11) & 3;
        int k = s * 32 + ((lane >> 4) << 3) + r;
        int n = (j << 4) + (lane & 15);
        f2[e] = f2bf(w2[L * 8192 + k * 64 + n]);
    }
}

// ---------------- input projection via MFMA ----------------
__global__ __launch_bounds__(256) void k_inproj_mfma(const float* __restrict__ x,
                                                     const unsigned short* __restrict__ wfrag,
                                                     const float* __restrict__ in_b,
                                                     float* __restrict__ h,
                                                     unsigned short* __restrict__ hb) {
    __shared__ unsigned short lw[12288];  // 24 KB
    const int tid = threadIdx.x;
    {
        const bf16x8* src = (const bf16x8*)wfrag;
        bf16x8* dst = (bf16x8*)lw;
        for (int i = tid; i < 1536; i += 256) dst[i] = src[i];
    }
    __syncthreads();
    const int wv = tid >> 6, lane = tid & 63;
    const int lrow = lane & 15, lgrp = lane >> 4;
    float ib[4];
#pragma unroll
    for (int j = 0; j < 4; ++j) ib[j] = in_b[16 * j + lrow];
    const int nwaves = gridDim.x * 4;
    for (int tile = blockIdx.x * 4 + wv; tile < 3125; tile += nwaves) {
        const int m0 = tile * 16;
        f32x4 acc[4];
#pragma unroll
        for (int j = 0; j < 4; ++j) acc[j] = (f32x4){ib[j], ib[j], ib[j], ib[j]};
#pragma unroll
        for (int s = 0; s < 6; ++s) {
            const int kbase = s * 32 + lgrp * 8;
            bf16x8 a;
            if (kbase < NODE_FEAT) {
                const float* p = x + (size_t)(m0 + lrow) * NODE_FEAT + kbase;
                float4 fa = *(const float4*)p;
                float4 fb = *(const float4*)(p + 4);
                a[0] = (short)f2bf(fa.x); a[1] = (short)f2bf(fa.y);
                a[2] = (short)f2bf(fa.z); a[3] = (short)f2bf(fa.w);
                a[4] = (short)f2bf(fb.x); a[5] = (short)f2bf(fb.y);
                a[6] = (short)f2bf(fb.z); a[7] = (short)f2bf(fb.w);
            } else {
                a = (bf16x8){0, 0, 0, 0, 0, 0, 0, 0};
            }
#pragma unroll
            for (int j = 0; j < 4; ++j) {
                bf16x8 b = *(const bf16x8*)&lw[((s * 4 + j) * 64 + lane) * 8];
                acc[j] = __builtin_amdgcn_mfma_f32_16x16x32_bf16(a, b, acc[j], 0, 0, 0);
            }
        }
#pragma unroll
        for (int j = 0; j < 4; ++j) {
            const int col = 16 * j + lrow;
#pragma unroll
            for (int r = 0; r < 4; ++r) {
                const int node = m0 + lgrp * 4 + r;
                float v = acc[j][r];
                h[(size_t)node * 64 + col] = v;
                hb[(size_t)node * 64 + col] = f2bf(v);
            }
        }
    }
}

// ---------------- CSR build ----------------
__global__ __launch_bounds__(256) void k_hist(const int* __restrict__ ei,
                                              int* __restrict__ cnt,
                                              int* __restrict__ erank) {
    int e = blockIdx.x * 256 + threadIdx.x;
    if (e < N_EDGES) erank[e] = atomicAdd(&cnt[ei[N_EDGES + e]], 1);
}

__global__ __launch_bounds__(256) void k_scan_part(const int* __restrict__ cnt,
                                                   int* __restrict__ blksum) {
    const int b = blockIdx.x, t = threadIdx.x;
    const int base = b * 1024 + t * 4;
    int s = 0;
#pragma unroll
    for (int i = 0; i < 4; ++i) {
        int idx = base + i;
        if (idx < N_NODES) s += cnt[idx];
    }
#pragma unroll
    for (int o = 32; o > 0; o >>= 1) s += __shfl_xor(s, o);
    __shared__ int wt[4];
    if ((t & 63) == 0) wt[t >> 6] = s;
    __syncthreads();
    if (t == 0) blksum[b] = wt[0] + wt[1] + wt[2] + wt[3];
}

__global__ __launch_bounds__(64) void k_scan_top(const int* __restrict__ blksum,
                                                 int* __restrict__ blkoff,
                                                 int* __restrict__ row_last) {
    const int t = threadIdx.x;
    int v = (t < SCAN_NB) ? blksum[t] : 0;
    int incl = v;
#pragma unroll
    for (int o = 1; o < 64; o <<= 1) {
        int u = __shfl_up(incl, o);
        if (t >= o) incl += u;
    }
    if (t < SCAN_NB) blkoff[t] = incl - v;
    if (t == 63) row_last[0] = incl;
}

__global__ __launch_bounds__(256) void k_scan_add(const int* __restrict__ cnt,
                                                  const int* __restrict__ blkoff,
                                                  int* __restrict__ row_ptr) {
    const int b = blockIdx.x, t = threadIdx.x;
    const int base = b * 1024 + t * 4;
    int c[4];
    int tsum = 0;
#pragma unroll
    for (int i = 0; i < 4; ++i) {
        int idx = base + i;
        c[i] = (idx < N_NODES) ? cnt[idx] : 0;
        tsum += c[i];
    }
    int incl = tsum;
#pragma unroll
    for (int o = 1; o < 64; o <<= 1) {
        int u = __shfl_up(incl, o);
        if ((t & 63) >= o) incl += u;
    }
    __shared__ int wt[4];
    const int wv = t >> 6;
    if ((t & 63) == 63) wt[wv] = incl;
    __syncthreads();
    int run = blkoff[b] + (incl - tsum);
    for (int w = 0; w < wv; ++w) run += wt[w];
#pragma unroll
    for (int i = 0; i < 4; ++i) {
        int idx = base + i;
        if (idx < N_NODES) row_ptr[idx] = run;
        run += c[i];
    }
}

// scatter (no atomics): pos = row_ptr[dst] + erank[e]; one 16B packed record
__global__ __launch_bounds__(256) void k_scatter(const int* __restrict__ ei,
                                                 const float4* __restrict__ ea,
                                                 const int* __restrict__ row_ptr,
                                                 const int* __restrict__ erank,
                                                 int4* __restrict__ rec) {
    int e = blockIdx.x * 256 + threadIdx.x;
    if (e >= N_EDGES) return;
    int d = ei[N_EDGES + e];
    float4 a = ea[e];
    int4 r;
    r.x = (int)(((unsigned)f2bf(a.y) << 16) | (unsigned)f2bf(a.x));
    r.y = (int)(((unsigned)f2bf(a.w) << 16) | (unsigned)f2bf(a.z));
    r.z = ei[e];
    r.w = 0;
    rec[row_ptr[d] + erank[e]] = r;
}

// ---------------- gather + aggregate (bf16 gathers, fp32 accum) ----------------
__global__ __launch_bounds__(256) void k_aggr(const float* __restrict__ h_in,
                                              const unsigned short* __restrict__ hb_in,
                                              float* __restrict__ z,
                                              const int* __restrict__ row_ptr,
                                              const int4* __restrict__ rec,
                                              const float* __restrict__ ew,
                                              const float* __restrict__ eb) {
    const int wv = threadIdx.x >> 6, lane = threadIdx.x & 63;
    const int node = blockIdx.x * 4 + wv;  // 12500*4 = 50000 exact
    const float ew0 = ew[0 * 64 + lane], ew1 = ew[1 * 64 + lane];
    const float ew2 = ew[2 * 64 + lane], ew3 = ew[3 * 64 + lane];
    const float ebl = eb[lane];
    const int beg = row_ptr[node];
    const int end = row_ptr[node + 1];
    float acc = h_in[(size_t)node * 64 + lane];
    int i = beg;
    const int n8 = beg + ((end - beg) & ~7);
    for (; i < n8; i += 8) {
        int4 r[8];
        float gg[8];
#pragma unroll
        for (int t = 0; t < 8; ++t) r[t] = rec[i + t];
#pragma unroll
        for (int t = 0; t < 8; ++t) gg[t] = bf2f(hb_in[(size_t)r[t].z * 64 + lane]);
#pragma unroll
        for (int t = 0; t < 8; ++t) {
            float a0 = bf2f((unsigned short)((unsigned)r[t].x & 0xffffu));
            float a1 = bf2f((unsigned short)((unsigned)r[t].x >> 16));
            float a2 = bf2f((unsigned short)((unsigned)r[t].y & 0xffffu));
            float a3 = bf2f((unsigned short)((unsigned)r[t].y >> 16));
            float v = fmaf(a0, ew0, fmaf(a1, ew1, fmaf(a2, ew2, fmaf(a3, ew3, ebl))));
            acc += fmaxf(v + gg[t], 0.0f);
        }
    }
    for (; i < end; ++i) {
        int4 r0 = rec[i];
        float g0 = bf2f(hb_in[(size_t)r0.z * 64 + lane]);
        float a0 = bf2f((unsigned short)((unsigned)r0.x & 0xffffu));
        float a1 = bf2f((unsigned short)((unsigned)r0.x >> 16));
        float a2 = bf2f((unsigned short)((unsigned)r0.y & 0xffffu));
        float a3 = bf2f((unsigned short)((unsigned)r0.y >> 16));
        float v = fmaf(a0, ew0, fmaf(a1, ew1, fmaf(a2, ew2, fmaf(a3, ew3, ebl))));
        acc += fmaxf(v + g0, 0.0f);
    }
    z[(size_t)node * 64 + lane] = acc;
}

// ---------------- MLP + LN + relu via MFMA (in-place on z) ----------------
__global__ __launch_bounds__(256) void k_mlp_mfma(float* __restrict__ z,
                                                  unsigned short* __restrict__ hb_out,
                                                  const unsigned short* __restrict__ f1,
                                                  const unsigned short* __restrict__ f2,
                                                  const float* __restrict__ b1,
                                                  const float* __restrict__ b2,
                                                  const float* __restrict__ lng,
                                                  const float* __restrict__ lnb) {
    __shared__ unsigned short w1f[8192];
    __shared__ unsigned short w2f[8192];
    __shared__ unsigned short z1s[4][2048];
    const int tid = threadIdx.x;
    {
        const bf16x8* s1 = (const bf16x8*)f1;
        const bf16x8* s2 = (const bf16x8*)f2;
        bf16x8* d1 = (bf16x8*)w1f;
        bf16x8* d2 = (bf16x8*)w2f;
        for (int i = tid; i < 1024; i += 256) { d1[i] = s1[i]; d2[i] = s2[i]; }
    }
    __syncthreads();
    const int wv = tid >> 6, lane = tid & 63;
    const int lrow = lane & 15, lgrp = lane >> 4;
    unsigned short* zs = z1s[wv];
    float bb1[8], bb2[4], g4[4], be4[4];
#pragma unroll
    for (int j = 0; j < 8; ++j) bb1[j] = b1[16 * j + lrow];
#pragma unroll
    for (int j = 0; j < 4; ++j) {
        bb2[j] = b2[16 * j + lrow];
        g4[j] = lng[16 * j + lrow];
        be4[j] = lnb[16 * j + lrow];
    }
    const int nwaves = gridDim.x * 4;
    for (int tile = blockIdx.x * 4 + wv; tile < 3125; tile += nwaves) {
        const int m0 = tile * 16;
        f32x4 acc1[8];
#pragma unroll
        for (int j = 0; j < 8; ++j) acc1[j] = (f32x4){bb1[j], bb1[j], bb1[j], bb1[j]};
#pragma unroll
        for (int s = 0; s < 2; ++s) {
            const int kbase = s * 32 + lgrp * 8;
            const float* p = z + (size_t)(m0 + lrow) * 64 + kbase;
            float4 fa = *(const float4*)p;
            float4 fb = *(const float4*)(p + 4);
            bf16x8 a;
            a[0] = (short)f2bf(fa.x); a[1] = (short)f2bf(fa.y);
            a[2] = (short)f2bf(fa.z); a[3] = (short)f2bf(fa.w);
            a[4] = (short)f2bf(fb.x); a[5] = (short)f2bf(fb.y);
            a[6] = (short)f2bf(fb.z); a[7] = (short)f2bf(fb.w);
#pragma unroll
            for (int j = 0; j < 8; ++j) {
                bf16x8 b = *(const bf16x8*)&w1f[((s * 8 + j) * 64 + lane) * 8];
                acc1[j] = __builtin_amdgcn_mfma_f32_16x16x32_bf16(a, b, acc1[j], 0, 0, 0);
            }
        }
#pragma unroll
        for (int j = 0; j < 8; ++j) {
            const int col = 16 * j + lrow;
#pragma unroll
            for (int r = 0; r < 4; ++r) {
                const int row = lgrp * 4 + r;
                const int idx = (row * 128 + col) ^ ((row & 7) << 3);
                zs[idx] = f2bf(fmaxf(acc1[j][r], 0.0f));
            }
        }
        f32x4 acc2[4];
#pragma unroll
        for (int j = 0; j < 4; ++j) acc2[j] = (f32x4){bb2[j], bb2[j], bb2[j], bb2[j]};
#pragma unroll
        for (int s = 0; s < 4; ++s) {
            const int kbase = s * 32 + lgrp * 8;
            const int idx = (lrow * 128 + kbase) ^ ((lrow & 7) << 3);
            bf16x8 a = *(const bf16x8*)&zs[idx];
#pragma unroll
            for (int j = 0; j < 4; ++j) {
                bf16x8 b = *(const bf16x8*)&w2f[((s * 4 + j) * 64 + lane) * 8];
                acc2[j] = __builtin_amdgcn_mfma_f32_16x16x32_bf16(a, b, acc2[j], 0, 0, 0);
            }
        }
#pragma unroll
        for (int r = 0; r < 4; ++r) {
            float sum = acc2[0][r] + acc2[1][r] + acc2[2][r] + acc2[3][r];
            sum = sum16(sum);
            const float mu = sum * (1.0f / 64.0f);
            float sq = 0.0f;
#pragma unroll
            for (int j = 0; j < 4; ++j) {
                float d = acc2[j][r] - mu;
                sq = fmaf(d, d, sq);
            }
            sq = sum16(sq);
            const float rstd = rsqrtf(sq * (1.0f / 64.0f) + LN_EPS);
            const int node = m0 + lgrp * 4 + r;
#pragma unroll
            for (int j = 0; j < 4; ++j) {
                const int col = 16 * j + lrow;
                float d = acc2[j][r] - mu;
                float hn = fmaxf(fmaf(g4[j] * d, rstd, be4[j]), 0.0f);
                z[(size_t)node * 64 + col] = hn;
                hb_out[(size_t)node * 64 + col] = f2bf(hn);
            }
        }
    }
}

// ---------------- pool + regressor ----------------
__global__ __launch_bounds__(256) void k_pool(const float* __restrict__ h,
                                              float* __restrict__ g) {
    __shared__ float red[256];
    const int tid = threadIdx.x;
    const int lane = tid & 63;
    float part = 0.0f;
    for (int i = blockIdx.x * 4 + (tid >> 6); i < N_NODES; i += gridDim.x * 4)
        part += h[(size_t)i * 64 + lane];
    red[tid] = part;
    __syncthreads();
    if (tid < 64) {
        float s = red[tid] + red[tid + 64] + red[tid + 128] + red[tid + 192];
        atomicAdd(&g[tid], s);
    }
}

__global__ __launch_bounds__(64) void k_reg(const float* __restrict__ g,
                                            const float* __restrict__ w1,
                                            const float* __restrict__ b1,
                                            const float* __restrict__ w2,
                                            const float* __restrict__ b2,
                                            float* __restrict__ out) {
    const int j = threadIdx.x;
    const int jm = j & 31;
    float acc = b1[jm];
#pragma unroll 8
    for (int k = 0; k < 64; ++k) {
        float gk = g[k];
        acc = fmaf(gk, w1[k * 32 + jm], acc);
    }
    float contrib = (j < 32) ? fmaxf(acc, 0.0f) * w2[jm] : 0.0f;
    float s = wave_sum64(contrib);
    if (j == 0) out[0] = s + b2[0];
}

extern "C" void kernel_launch(void* const* d_in, const int* in_sizes, int n_in,
                              void* d_out, int out_size, void* d_ws, size_t ws_size,
                              hipStream_t stream) {
    const float* x      = (const float*)d_in[0];
    const int*   ei     = (const int*)d_in[1];
    const float* ea     = (const float*)d_in[2];
    const float* in_w   = (const float*)d_in[3];
    const float* in_b   = (const float*)d_in[4];
    const float* edge_w = (const float*)d_in[5];
    const float* edge_b = (const float*)d_in[6];
    const float* mlp_w1 = (const float*)d_in[7];
    const float* mlp_b1 = (const float*)d_in[8];
    const float* mlp_w2 = (const float*)d_in[9];
    const float* mlp_b2 = (const float*)d_in[10];
    const float* ln_g   = (const float*)d_in[11];
    const float* ln_b   = (const float*)d_in[12];
    const float* reg_w1 = (const float*)d_in[13];
    const float* reg_b1 = (const float*)d_in[14];
    const float* reg_w2 = (const float*)d_in[15];
    const float* reg_b2 = (const float*)d_in[16];

    char* ws = (char*)d_ws;
    float*          h0      = (float*)ws;          ws += (size_t)N_NODES * 64 * 4;
    float*          h1      = (float*)ws;          ws += (size_t)N_NODES * 64 * 4;
    int4*           rec     = (int4*)ws;           ws += (size_t)N_EDGES * 16;
    unsigned short* hb0     = (unsigned short*)ws; ws += (size_t)N_NODES * 64 * 2;
    unsigned short* hb1     = (unsigned short*)ws; ws += (size_t)N_NODES * 64 * 2;
    unsigned short* fin     = (unsigned short*)ws; ws += 12288 * 2;
    unsigned short* f1      = (unsigned short*)ws; ws += 32768 * 2;
    unsigned short* f2      = (unsigned short*)ws; ws += 32768 * 2;
    int*            erank   = (int*)ws;            ws += (size_t)N_EDGES * 4;
    int*            row_ptr = (int*)ws;            ws += (size_t)(N_NODES + 1) * 4;
    int*            cnt     = (int*)ws;            ws += (size_t)N_NODES * 4;
    int*            blksum  = (int*)ws;            ws += SCAN_NB * 4;
    int*            blkoff  = (int*)ws;            ws += SCAN_NB * 4;
    float*          g       = (float*)ws;          ws += 64 * 4;
    float*          outf    = (float*)d_out;

    const int eb_blocks = (N_EDGES + 255) / 256;

    k_wprep<<<304, 256, 0, stream>>>(in_w, mlp_w1, mlp_w2, fin, f1, f2);

    hipMemsetAsync(cnt, 0, N_NODES * sizeof(int), stream);
    k_hist<<<eb_blocks, 256, 0, stream>>>(ei, cnt, erank);
    k_scan_part<<<SCAN_NB, 256, 0, stream>>>(cnt, blksum);
    k_scan_top<<<1, 64, 0, stream>>>(blksum, blkoff, row_ptr + N_NODES);
    k_scan_add<<<SCAN_NB, 256, 0, stream>>>(cnt, blkoff, row_ptr);
    k_scatter<<<eb_blocks, 256, 0, stream>>>(ei, (const float4*)ea, row_ptr, erank, rec);

    k_inproj_mfma<<<256, 256, 0, stream>>>(x, fin, in_b, h0, hb0);

    float* hA = h0;
    float* hB = h1;
    unsigned short* hbA = hb0;
    unsigned short* hbB = hb1;
    for (int l = 0; l < 4; ++l) {
        k_aggr<<<N_NODES / 4, 256, 0, stream>>>(hA, hbA, hB, row_ptr, rec,
                                                edge_w + l * 4 * 64,
                                                edge_b + l * 64);
        k_mlp_mfma<<<256, 256, 0, stream>>>(hB, hbB,
                                            f1 + l * 8192, f2 + l * 8192,
                                            mlp_b1 + l * 128, mlp_b2 + l * 64,
                                            ln_g + l * 64, ln_b + l * 64);
        float* t = hA; hA = hB; hB = t;
        unsigned short* tb = hbA; hbA = hbB; hbB = tb;
    }

    hipMemsetAsync(g, 0, 64 * sizeof(float), stream);
    k_pool<<<256, 256, 0, stream>>>(hA, g);
    k_reg<<<1, 64, 0, stream>>>(g, reg_w1, reg_b1, reg_w2, reg_b2, outf);
}

// Round 8
// 287.364 us; speedup vs baseline: 4.0170x; 1.1737x over previous
//
#include <hip/hip_runtime.h>

#define N_NODES 50000
#define N_EDGES 800000
#define NODE_FEAT 176
#define HIDDEN 64
#define LN_EPS 1e-5f
#define SCAN_NB 49  // ceil(50000/1024)

typedef short bf16x8 __attribute__((ext_vector_type(8)));
typedef float f32x4 __attribute__((ext_vector_type(4)));

__device__ __forceinline__ unsigned short f2bf(float f) {
    unsigned int u = __float_as_uint(f);
    u += 0x7FFFu + ((u >> 16) & 1u);  // round-to-nearest-even
    return (unsigned short)(u >> 16);
}
__device__ __forceinline__ int pack2(float lo, float hi) {
    return (int)(((unsigned)f2bf(hi) << 16) | (unsigned)f2bf(lo));
}
__device__ __forceinline__ float bf2f(unsigned short s) {
    return __uint_as_float(((unsigned int)s) << 16);
}
__device__ __forceinline__ float wave_sum64(float v) {
#pragma unroll
    for (int o = 32; o > 0; o >>= 1) v += __shfl_xor(v, o);
    return v;
}
__device__ __forceinline__ float sum16(float v) {
#pragma unroll
    for (int o = 8; o > 0; o >>= 1) v += __shfl_xor(v, o);
    return v;
}

// ---------------- weight prep: bf16 MFMA B-fragment swizzle ----------------
__global__ __launch_bounds__(256) void k_wprep(const float* __restrict__ in_w,
                                               const float* __restrict__ w1,
                                               const float* __restrict__ w2,
                                               unsigned short* __restrict__ fin,
                                               unsigned short* __restrict__ f1,
                                               unsigned short* __restrict__ f2) {
    int t = blockIdx.x * 256 + threadIdx.x;
    if (t < 12288) {  // in_w: [176->192 pad][64], 6 slices x 4 ntiles
        int e = t;
        int r = e & 7, lane = (e >> 3) & 63, j = (e >> 9) & 3, s = e >> 11;
        int k = s * 32 + ((lane >> 4) << 3) + r;
        int n = (j << 4) + (lane & 15);
        fin[e] = (k < NODE_FEAT) ? f2bf(in_w[k * 64 + n]) : (unsigned short)0;
    } else if (t < 12288 + 32768) {  // w1: 4 layers x [64][128]
        int e = t - 12288;
        int L = e >> 13, e2 = e & 8191;
        int r = e2 & 7, lane = (e2 >> 3) & 63, j = (e2 >> 9) & 7, s = (e2 >> 12) & 1;
        int k = s * 32 + ((lane >> 4) << 3) + r;
        int n = (j << 4) + (lane & 15);
        f1[e] = f2bf(w1[L * 8192 + k * 128 + n]);
    } else {  // w2: 4 layers x [128][64]
        int e = t - 45056;
        int L = e >> 13, e2 = e & 8191;
        int r = e2 & 7, lane = (e2 >> 3) & 63, j = (e2 >> 9) & 3, s = (e2 >> 11) & 3;
        int k = s * 32 + ((lane >> 4) << 3) + r;
        int n = (j << 4) + (lane & 15);
        f2[e] = f2bf(w2[L * 8192 + k * 64 + n]);
    }
}

// ---------------- input projection via MFMA ----------------
__global__ __launch_bounds__(256) void k_inproj_mfma(const float* __restrict__ x,
                                                     const unsigned short* __restrict__ wfrag,
                                                     const float* __restrict__ in_b,
                                                     float* __restrict__ h,
                                                     unsigned short* __restrict__ hb) {
    __shared__ unsigned short lw[12288];  // 24 KB
    const int tid = threadIdx.x;
    {
        const bf16x8* src = (const bf16x8*)wfrag;
        bf16x8* dst = (bf16x8*)lw;
        for (int i = tid; i < 1536; i += 256) dst[i] = src[i];
    }
    __syncthreads();
    const int wv = tid >> 6, lane = tid & 63;
    const int lrow = lane & 15, lgrp = lane >> 4;
    float ib[4];
#pragma unroll
    for (int j = 0; j < 4; ++j) ib[j] = in_b[16 * j + lrow];
    const int nwaves = gridDim.x * 4;
    for (int tile = blockIdx.x * 4 + wv; tile < 3125; tile += nwaves) {
        const int m0 = tile * 16;
        f32x4 acc[4];
#pragma unroll
        for (int j = 0; j < 4; ++j) acc[j] = (f32x4){ib[j], ib[j], ib[j], ib[j]};
#pragma unroll
        for (int s = 0; s < 6; ++s) {
            const int kbase = s * 32 + lgrp * 8;
            bf16x8 a;
            if (kbase < NODE_FEAT) {
                const float* p = x + (size_t)(m0 + lrow) * NODE_FEAT + kbase;
                float4 fa = *(const float4*)p;
                float4 fb = *(const float4*)(p + 4);
                a[0] = (short)f2bf(fa.x); a[1] = (short)f2bf(fa.y);
                a[2] = (short)f2bf(fa.z); a[3] = (short)f2bf(fa.w);
                a[4] = (short)f2bf(fb.x); a[5] = (short)f2bf(fb.y);
                a[6] = (short)f2bf(fb.z); a[7] = (short)f2bf(fb.w);
            } else {
                a = (bf16x8){0, 0, 0, 0, 0, 0, 0, 0};
            }
#pragma unroll
            for (int j = 0; j < 4; ++j) {
                bf16x8 b = *(const bf16x8*)&lw[((s * 4 + j) * 64 + lane) * 8];
                acc[j] = __builtin_amdgcn_mfma_f32_16x16x32_bf16(a, b, acc[j], 0, 0, 0);
            }
        }
#pragma unroll
        for (int j = 0; j < 4; ++j) {
            const int col = 16 * j + lrow;
#pragma unroll
            for (int r = 0; r < 4; ++r) {
                const int node = m0 + lgrp * 4 + r;
                float v = acc[j][r];
                h[(size_t)node * 64 + col] = v;
                hb[(size_t)node * 64 + col] = f2bf(v);
            }
        }
    }
}

// ---------------- CSR build ----------------
__global__ __launch_bounds__(256) void k_hist(const int* __restrict__ ei,
                                              int* __restrict__ cnt,
                                              int* __restrict__ erank) {
    int e = blockIdx.x * 256 + threadIdx.x;
    if (e < N_EDGES) erank[e] = atomicAdd(&cnt[ei[N_EDGES + e]], 1);
}

__global__ __launch_bounds__(256) void k_scan_part(const int* __restrict__ cnt,
                                                   int* __restrict__ blksum) {
    const int b = blockIdx.x, t = threadIdx.x;
    const int base = b * 1024 + t * 4;
    int s = 0;
#pragma unroll
    for (int i = 0; i < 4; ++i) {
        int idx = base + i;
        if (idx < N_NODES) s += cnt[idx];
    }
#pragma unroll
    for (int o = 32; o > 0; o >>= 1) s += __shfl_xor(s, o);
    __shared__ int wt[4];
    if ((t & 63) == 0) wt[t >> 6] = s;
    __syncthreads();
    if (t == 0) blksum[b] = wt[0] + wt[1] + wt[2] + wt[3];
}

__global__ __launch_bounds__(64) void k_scan_top(const int* __restrict__ blksum,
                                                 int* __restrict__ blkoff,
                                                 int* __restrict__ row_last) {
    const int t = threadIdx.x;
    int v = (t < SCAN_NB) ? blksum[t] : 0;
    int incl = v;
#pragma unroll
    for (int o = 1; o < 64; o <<= 1) {
        int u = __shfl_up(incl, o);
        if (t >= o) incl += u;
    }
    if (t < SCAN_NB) blkoff[t] = incl - v;
    if (t == 63) row_last[0] = incl;
}

__global__ __launch_bounds__(256) void k_scan_add(const int* __restrict__ cnt,
                                                  const int* __restrict__ blkoff,
                                                  int* __restrict__ row_ptr) {
    const int b = blockIdx.x, t = threadIdx.x;
    const int base = b * 1024 + t * 4;
    int c[4];
    int tsum = 0;
#pragma unroll
    for (int i = 0; i < 4; ++i) {
        int idx = base + i;
        c[i] = (idx < N_NODES) ? cnt[idx] : 0;
        tsum += c[i];
    }
    int incl = tsum;
#pragma unroll
    for (int o = 1; o < 64; o <<= 1) {
        int u = __shfl_up(incl, o);
        if ((t & 63) >= o) incl += u;
    }
    __shared__ int wt[4];
    const int wv = t >> 6;
    if ((t & 63) == 63) wt[wv] = incl;
    __syncthreads();
    int run = blkoff[b] + (incl - tsum);
    for (int w = 0; w < wv; ++w) run += wt[w];
#pragma unroll
    for (int i = 0; i < 4; ++i) {
        int idx = base + i;
        if (idx < N_NODES) row_ptr[idx] = run;
        run += c[i];
    }
}

// scatter (no atomics): pos = row_ptr[dst] + erank[e]; one 16B packed record
__global__ __launch_bounds__(256) void k_scatter(const int* __restrict__ ei,
                                                 const float4* __restrict__ ea,
                                                 const int* __restrict__ row_ptr,
                                                 const int* __restrict__ erank,
                                                 int4* __restrict__ rec) {
    int e = blockIdx.x * 256 + threadIdx.x;
    if (e >= N_EDGES) return;
    int d = ei[N_EDGES + e];
    float4 a = ea[e];
    int4 r;
    r.x = pack2(a.x, a.y);
    r.y = pack2(a.z, a.w);
    r.z = ei[e];
    r.w = 0;
    rec[row_ptr[d] + erank[e]] = r;
}

// ---------------- gather + aggregate ----------------
// wave-per-node. All edge metadata is wave-uniform -> forced to SGPRs via
// readfirstlane; attr bf16->f32 unpack is SALU (<<16 / mask). Only the
// gather + 7 math ops stay on the VALU.
__global__ __launch_bounds__(256) void k_aggr(const float* __restrict__ h_in,
                                              const unsigned short* __restrict__ hb_in,
                                              float* __restrict__ z,
                                              const int* __restrict__ row_ptr,
                                              const int4* __restrict__ rec,
                                              const float* __restrict__ ew,
                                              const float* __restrict__ eb) {
    const int wv = threadIdx.x >> 6, lane = threadIdx.x & 63;
    const int node = blockIdx.x * 4 + wv;  // 12500*4 = 50000 exact
    const float ew0 = ew[0 * 64 + lane], ew1 = ew[1 * 64 + lane];
    const float ew2 = ew[2 * 64 + lane], ew3 = ew[3 * 64 + lane];
    const float ebl = eb[lane];
    const int beg = __builtin_amdgcn_readfirstlane(row_ptr[node]);
    const int end = __builtin_amdgcn_readfirstlane(row_ptr[node + 1]);
    float acc = h_in[(size_t)node * 64 + lane];
    int i = beg;
    for (; i + 7 < end; i += 8) {
        int d0[8], d1[8], sx[8];
#pragma unroll
        for (int t = 0; t < 8; ++t) {
            int4 r = rec[i + t];
            d0[t] = __builtin_amdgcn_readfirstlane(r.x);
            d1[t] = __builtin_amdgcn_readfirstlane(r.y);
            sx[t] = __builtin_amdgcn_readfirstlane(r.z);
        }
        float gg[8];
#pragma unroll
        for (int t = 0; t < 8; ++t) {
            const unsigned short* __restrict__ p = hb_in + ((size_t)sx[t] << 6);
            gg[t] = bf2f(p[lane]);
        }
#pragma unroll
        for (int t = 0; t < 8; ++t) {
            float a0 = __uint_as_float((unsigned)d0[t] << 16);
            float a1 = __uint_as_float((unsigned)d0[t] & 0xffff0000u);
            float a2 = __uint_as_float((unsigned)d1[t] << 16);
            float a3 = __uint_as_float((unsigned)d1[t] & 0xffff0000u);
            float v = fmaf(a0, ew0, fmaf(a1, ew1, fmaf(a2, ew2, fmaf(a3, ew3, ebl))));
            acc += fmaxf(v + gg[t], 0.0f);
        }
    }
    for (; i < end; ++i) {
        int4 r = rec[i];
        int d0 = __builtin_amdgcn_readfirstlane(r.x);
        int d1 = __builtin_amdgcn_readfirstlane(r.y);
        int sx = __builtin_amdgcn_readfirstlane(r.z);
        const unsigned short* __restrict__ p = hb_in + ((size_t)sx << 6);
        float g0 = bf2f(p[lane]);
        float a0 = __uint_as_float((unsigned)d0 << 16);
        float a1 = __uint_as_float((unsigned)d0 & 0xffff0000u);
        float a2 = __uint_as_float((unsigned)d1 << 16);
        float a3 = __uint_as_float((unsigned)d1 & 0xffff0000u);
        float v = fmaf(a0, ew0, fmaf(a1, ew1, fmaf(a2, ew2, fmaf(a3, ew3, ebl))));
        acc += fmaxf(v + g0, 0.0f);
    }
    z[(size_t)node * 64 + lane] = acc;
}

// ---------------- MLP + LN + relu via MFMA (in-place on z) ----------------
__global__ __launch_bounds__(256) void k_mlp_mfma(float* __restrict__ z,
                                                  unsigned short* __restrict__ hb_out,
                                                  const unsigned short* __restrict__ f1,
                                                  const unsigned short* __restrict__ f2,
                                                  const float* __restrict__ b1,
                                                  const float* __restrict__ b2,
                                                  const float* __restrict__ lng,
                                                  const float* __restrict__ lnb) {
    __shared__ unsigned short w1f[8192];
    __shared__ unsigned short w2f[8192];
    __shared__ unsigned short z1s[4][2048];
    const int tid = threadIdx.x;
    {
        const bf16x8* s1 = (const bf16x8*)f1;
        const bf16x8* s2 = (const bf16x8*)f2;
        bf16x8* d1 = (bf16x8*)w1f;
        bf16x8* d2 = (bf16x8*)w2f;
        for (int i = tid; i < 1024; i += 256) { d1[i] = s1[i]; d2[i] = s2[i]; }
    }
    __syncthreads();
    const int wv = tid >> 6, lane = tid & 63;
    const int lrow = lane & 15, lgrp = lane >> 4;
    unsigned short* zs = z1s[wv];
    float bb1[8], bb2[4], g4[4], be4[4];
#pragma unroll
    for (int j = 0; j < 8; ++j) bb1[j] = b1[16 * j + lrow];
#pragma unroll
    for (int j = 0; j < 4; ++j) {
        bb2[j] = b2[16 * j + lrow];
        g4[j] = lng[16 * j + lrow];
        be4[j] = lnb[16 * j + lrow];
    }
    const int nwaves = gridDim.x * 4;
    for (int tile = blockIdx.x * 4 + wv; tile < 3125; tile += nwaves) {
        const int m0 = tile * 16;
        f32x4 acc1[8];
#pragma unroll
        for (int j = 0; j < 8; ++j) acc1[j] = (f32x4){bb1[j], bb1[j], bb1[j], bb1[j]};
#pragma unroll
        for (int s = 0; s < 2; ++s) {
            const int kbase = s * 32 + lgrp * 8;
            const float* p = z + (size_t)(m0 + lrow) * 64 + kbase;
            float4 fa = *(const float4*)p;
            float4 fb = *(const float4*)(p + 4);
            bf16x8 a;
            a[0] = (short)f2bf(fa.x); a[1] = (short)f2bf(fa.y);
            a[2] = (short)f2bf(fa.z); a[3] = (short)f2bf(fa.w);
            a[4] = (short)f2bf(fb.x); a[5] = (short)f2bf(fb.y);
            a[6] = (short)f2bf(fb.z); a[7] = (short)f2bf(fb.w);
#pragma unroll
            for (int j = 0; j < 8; ++j) {
                bf16x8 b = *(const bf16x8*)&w1f[((s * 8 + j) * 64 + lane) * 8];
                acc1[j] = __builtin_amdgcn_mfma_f32_16x16x32_bf16(a, b, acc1[j], 0, 0, 0);
            }
        }
#pragma unroll
        for (int j = 0; j < 8; ++j) {
            const int col = 16 * j + lrow;
#pragma unroll
            for (int r = 0; r < 4; ++r) {
                const int row = lgrp * 4 + r;
                const int idx = (row * 128 + col) ^ ((row & 7) << 3);
                zs[idx] = f2bf(fmaxf(acc1[j][r], 0.0f));
            }
        }
        f32x4 acc2[4];
#pragma unroll
        for (int j = 0; j < 4; ++j) acc2[j] = (f32x4){bb2[j], bb2[j], bb2[j], bb2[j]};
#pragma unroll
        for (int s = 0; s < 4; ++s) {
            const int kbase = s * 32 + lgrp * 8;
            const int idx = (lrow * 128 + kbase) ^ ((lrow & 7) << 3);
            bf16x8 a = *(const bf16x8*)&zs[idx];
#pragma unroll
            for (int j = 0; j < 4; ++j) {
                bf16x8 b = *(const bf16x8*)&w2f[((s * 4 + j) * 64 + lane) * 8];
                acc2[j] = __builtin_amdgcn_mfma_f32_16x16x32_bf16(a, b, acc2[j], 0, 0, 0);
            }
        }
#pragma unroll
        for (int r = 0; r < 4; ++r) {
            float sum = acc2[0][r] + acc2[1][r] + acc2[2][r] + acc2[3][r];
            sum = sum16(sum);
            const float mu = sum * (1.0f / 64.0f);
            float sq = 0.0f;
#pragma unroll
            for (int j = 0; j < 4; ++j) {
                float d = acc2[j][r] - mu;
                sq = fmaf(d, d, sq);
            }
            sq = sum16(sq);
            const float rstd = rsqrtf(sq * (1.0f / 64.0f) + LN_EPS);
            const int node = m0 + lgrp * 4 + r;
#pragma unroll
            for (int j = 0; j < 4; ++j) {
                const int col = 16 * j + lrow;
                float d = acc2[j][r] - mu;
                float hn = fmaxf(fmaf(g4[j] * d, rstd, be4[j]), 0.0f);
                z[(size_t)node * 64 + col] = hn;
                hb_out[(size_t)node * 64 + col] = f2bf(hn);
            }
        }
    }
}

// ---------------- pool + regressor ----------------
__global__ __launch_bounds__(256) void k_pool(const float* __restrict__ h,
                                              float* __restrict__ g) {
    __shared__ float red[256];
    const int tid = threadIdx.x;
    const int lane = tid & 63;
    float part = 0.0f;
    for (int i = blockIdx.x * 4 + (tid >> 6); i < N_NODES; i += gridDim.x * 4)
        part += h[(size_t)i * 64 + lane];
    red[tid] = part;
    __syncthreads();
    if (tid < 64) {
        float s = red[tid] + red[tid + 64] + red[tid + 128] + red[tid + 192];
        atomicAdd(&g[tid], s);
    }
}

__global__ __launch_bounds__(64) void k_reg(const float* __restrict__ g,
                                            const float* __restrict__ w1,
                                            const float* __restrict__ b1,
                                            const float* __restrict__ w2,
                                            const float* __restrict__ b2,
                                            float* __restrict__ out) {
    const int j = threadIdx.x;
    const int jm = j & 31;
    float acc = b1[jm];
#pragma unroll 8
    for (int k = 0; k < 64; ++k) {
        float gk = g[k];
        acc = fmaf(gk, w1[k * 32 + jm], acc);
    }
    float contrib = (j < 32) ? fmaxf(acc, 0.0f) * w2[jm] : 0.0f;
    float s = wave_sum64(contrib);
    if (j == 0) out[0] = s + b2[0];
}

extern "C" void kernel_launch(void* const* d_in, const int* in_sizes, int n_in,
                              void* d_out, int out_size, void* d_ws, size_t ws_size,
                              hipStream_t stream) {
    const float* x      = (const float*)d_in[0];
    const int*   ei     = (const int*)d_in[1];
    const float* ea     = (const float*)d_in[2];
    const float* in_w   = (const float*)d_in[3];
    const float* in_b   = (const float*)d_in[4];
    const float* edge_w = (const float*)d_in[5];
    const float* edge_b = (const float*)d_in[6];
    const float* mlp_w1 = (const float*)d_in[7];
    const float* mlp_b1 = (const float*)d_in[8];
    const float* mlp_w2 = (const float*)d_in[9];
    const float* mlp_b2 = (const float*)d_in[10];
    const float* ln_g   = (const float*)d_in[11];
    const float* ln_b   = (const float*)d_in[12];
    const float* reg_w1 = (const float*)d_in[13];
    const float* reg_b1 = (const float*)d_in[14];
    const float* reg_w2 = (const float*)d_in[15];
    const float* reg_b2 = (const float*)d_in[16];

    char* ws = (char*)d_ws;
    float*          h0      = (float*)ws;          ws += (size_t)N_NODES * 64 * 4;
    float*          h1      = (float*)ws;          ws += (size_t)N_NODES * 64 * 4;
    int4*           rec     = (int4*)ws;           ws += (size_t)N_EDGES * 16;
    unsigned short* hb0     = (unsigned short*)ws; ws += (size_t)N_NODES * 64 * 2;
    unsigned short* hb1     = (unsigned short*)ws; ws += (size_t)N_NODES * 64 * 2;
    unsigned short* fin     = (unsigned short*)ws; ws += 12288 * 2;
    unsigned short* f1      = (unsigned short*)ws; ws += 32768 * 2;
    unsigned short* f2      = (unsigned short*)ws; ws += 32768 * 2;
    int*            erank   = (int*)ws;            ws += (size_t)N_EDGES * 4;
    int*            row_ptr = (int*)ws;            ws += (size_t)(N_NODES + 1) * 4;
    int*            cnt     = (int*)ws;            ws += (size_t)N_NODES * 4;
    int*            blksum  = (int*)ws;            ws += SCAN_NB * 4;
    int*            blkoff  = (int*)ws;            ws += SCAN_NB * 4;
    float*          g       = (float*)ws;          ws += 64 * 4;
    float*          outf    = (float*)d_out;

    const int eb_blocks = (N_EDGES + 255) / 256;

    k_wprep<<<304, 256, 0, stream>>>(in_w, mlp_w1, mlp_w2, fin, f1, f2);

    (void)hipMemsetAsync(cnt, 0, N_NODES * sizeof(int), stream);
    k_hist<<<eb_blocks, 256, 0, stream>>>(ei, cnt, erank);
    k_scan_part<<<SCAN_NB, 256, 0, stream>>>(cnt, blksum);
    k_scan_top<<<1, 64, 0, stream>>>(blksum, blkoff, row_ptr + N_NODES);
    k_scan_add<<<SCAN_NB, 256, 0, stream>>>(cnt, blkoff, row_ptr);
    k_scatter<<<eb_blocks, 256, 0, stream>>>(ei, (const float4*)ea, row_ptr, erank, rec);

    k_inproj_mfma<<<512, 256, 0, stream>>>(x, fin, in_b, h0, hb0);

    float* hA = h0;
    float* hB = h1;
    unsigned short* hbA = hb0;
    unsigned short* hbB = hb1;
    for (int l = 0; l < 4; ++l) {
        k_aggr<<<N_NODES / 4, 256, 0, stream>>>(hA, hbA, hB, row_ptr, rec,
                                                edge_w + l * 4 * 64,
                                                edge_b + l * 64);
        k_mlp_mfma<<<256, 256, 0, stream>>>(hB, hbB,
                                            f1 + l * 8192, f2 + l * 8192,
                                            mlp_b1 + l * 128, mlp_b2 + l * 64,
                                            ln_g + l * 64, ln_b + l * 64);
        float* t = hA; hA = hB; hB = t;
        unsigned short* tb = hbA; hbA = hbB; hbB = tb;
    }

    (void)hipMemsetAsync(g, 0, 64 * sizeof(float), stream);
    k_pool<<<256, 256, 0, stream>>>(hA, g);
    k_reg<<<1, 64, 0, stream>>>(g, reg_w1, reg_b1, reg_w2, reg_b2, outf);
}